// Round 1
// 290.689 us; speedup vs baseline: 1.0311x; 1.0311x over previous
//
#include <hip/hip_runtime.h>
#include <hip/hip_bf16.h>
#include <math.h>

typedef __hip_bfloat16 bf16;
typedef __attribute__((ext_vector_type(8))) short short8;
typedef __attribute__((ext_vector_type(4))) float f32x4;

#define MFMA_BF16(a, b, c) __builtin_amdgcn_mfma_f32_16x16x32_bf16((a), (b), (c), 0, 0, 0)

// async global->LDS, 16B per lane (m97 pattern). LDS dest must be base + lane*16.
__device__ __forceinline__ void async_copy16(const bf16* g, bf16* l) {
  __builtin_amdgcn_global_load_lds(
      (const __attribute__((address_space(1))) void*)g,
      (__attribute__((address_space(3))) void*)l,
      16, 0, 0);
}

__device__ __forceinline__ unsigned short f2bf_bits(float f) {
  bf16 h = __float2bfloat16(f);
  return *reinterpret_cast<unsigned short*>(&h);
}

// pack 2 f32 -> 2 bf16 in one u32 (lo = first arg). No builtin on gfx950 (m240).
__device__ __forceinline__ unsigned cvt_pk_bf16(float lo, float hi) {
  unsigned r;
  asm("v_cvt_pk_bf16_f32 %0, %1, %2" : "=v"(r) : "v"(lo), "v"(hi));
  return r;
}

// ------------------------------------------- all fp32 -> bf16 in one launch
// blocks [0,8192): x ; [8192,9216): Wq (pre-scaled by 0.125*log2e so softmax
// scale is folded into the Q projection) ; [9216,10240): Wk ; [10240,11264): Wv ;
// [11264,12288): Wp. One float4 per thread.
__global__ __launch_bounds__(256) void cvt_all(const float* __restrict__ x,
                                               const float* __restrict__ wq,
                                               const float* __restrict__ wk,
                                               const float* __restrict__ wv,
                                               const float* __restrict__ wp,
                                               bf16* __restrict__ xb, bf16* __restrict__ wqb,
                                               bf16* __restrict__ wkb, bf16* __restrict__ wvb,
                                               bf16* __restrict__ wpb) {
  const int bid = blockIdx.x;
  const float* in;
  bf16* out;
  int off;
  float scale = 1.0f;
  if (bid < 8192) {
    in = x; out = xb; off = bid;
  } else if (bid < 9216) {
    in = wq; out = wqb; off = bid - 8192;
    scale = 0.180336880111112f;  // 0.125 * log2(e)
  } else if (bid < 10240) {
    in = wk; out = wkb; off = bid - 9216;
  } else if (bid < 11264) {
    in = wv; out = wvb; off = bid - 10240;
  } else {
    in = wp; out = wpb; off = bid - 11264;
  }
  const int i = off * 256 + threadIdx.x;
  float4 v = reinterpret_cast<const float4*>(in)[i];
  ushort4 u;
  u.x = f2bf_bits(v.x * scale);
  u.y = f2bf_bits(v.y * scale);
  u.z = f2bf_bits(v.z * scale);
  u.w = f2bf_bits(v.w * scale);
  reinterpret_cast<ushort4*>(out)[i] = u;
}

// ------------------------------------------------- 128x128 GEMM core (C = A*W^T)
__device__ __forceinline__ void gemm_core(const bf16* __restrict__ A,
                                          const bf16* __restrict__ W,
                                          bf16* As, bf16* Bs, f32x4 (&acc)[4][4]) {
  const int tid = threadIdx.x;
  const int lane = tid & 63;
  const int l15 = lane & 15;
  const int quad = lane >> 4;
  const int wave = tid >> 6;
  const int wm = (wave >> 1) * 64;
  const int wn = (wave & 1) * 64;
  const int K = 1024;

  const f32x4 zero = {0.f, 0.f, 0.f, 0.f};
#pragma unroll
  for (int i = 0; i < 4; ++i)
#pragma unroll
    for (int j = 0; j < 4; ++j) acc[i][j] = zero;

  const int srow = tid >> 2;
  const int scol = (tid & 3) * 8;
  const bf16* ga = A + (size_t)(blockIdx.y * 128 + srow) * K + scol;
  const bf16* gb = W + (size_t)(blockIdx.x * 128 + srow) * K + scol;
  bf16* lA = As + tid * 8;
  bf16* lB = Bs + tid * 8;

  for (int kt = 0; kt < 32; ++kt) {
    const int k0 = kt * 32;
    async_copy16(ga + k0, lA);
    async_copy16(ga + k0 + 64 * K, lA + 2048);
    async_copy16(gb + k0, lB);
    async_copy16(gb + k0 + 64 * K, lB + 2048);
    __syncthreads();
    short8 afr[4], bfr[4];
#pragma unroll
    for (int i = 0; i < 4; ++i)
      afr[i] = *reinterpret_cast<const short8*>(As + (wm + i * 16 + l15) * 32 + quad * 8);
#pragma unroll
    for (int j = 0; j < 4; ++j)
      bfr[j] = *reinterpret_cast<const short8*>(Bs + (wn + j * 16 + l15) * 32 + quad * 8);
#pragma unroll
    for (int i = 0; i < 4; ++i)
#pragma unroll
      for (int j = 0; j < 4; ++j) acc[i][j] = MFMA_BF16(afr[i], bfr[j], acc[i][j]);
    __syncthreads();
  }
}

// fused q/k/v projection: grid (8, 64, 3). z==2 (V) writes TRANSPOSED into
// vt[(b*1024 + col)*2048 + t] (i.e. [bh][d][t]).
__global__ __launch_bounds__(256) void gemm_qkv(const bf16* __restrict__ x,
                                                const bf16* __restrict__ wq,
                                                const bf16* __restrict__ wk,
                                                const bf16* __restrict__ wv,
                                                bf16* __restrict__ q, bf16* __restrict__ k,
                                                bf16* __restrict__ vt) {
  __shared__ __align__(16) bf16 As[128 * 32];
  __shared__ __align__(16) bf16 Bs[128 * 32];
  const bf16* W = (blockIdx.z == 0) ? wq : (blockIdx.z == 1) ? wk : wv;
  f32x4 acc[4][4];
  gemm_core(x, W, As, Bs, acc);
  const int tid = threadIdx.x, lane = tid & 63, l15 = lane & 15, quad = lane >> 4,
            wave = tid >> 6;
  const int wm = (wave >> 1) * 64, wn = (wave & 1) * 64;
  const int rb = blockIdx.y * 128 + wm + quad * 4;
  const int cb = blockIdx.x * 128 + wn + l15;
  if (blockIdx.z == 2) {
#pragma unroll
    for (int i = 0; i < 4; ++i)
#pragma unroll
      for (int j = 0; j < 4; ++j) {
        const int tg = rb + i * 16;
        const int col = cb + j * 16;
        const int b = tg >> 11, tl = tg & 2047;
        ushort4 pk;
        pk.x = f2bf_bits(acc[i][j][0]);
        pk.y = f2bf_bits(acc[i][j][1]);
        pk.z = f2bf_bits(acc[i][j][2]);
        pk.w = f2bf_bits(acc[i][j][3]);
        *reinterpret_cast<ushort4*>(&vt[((size_t)(b * 1024 + col)) * 2048 + tl]) = pk;
      }
  } else {
    bf16* C = (blockIdx.z == 0) ? q : k;
#pragma unroll
    for (int i = 0; i < 4; ++i)
#pragma unroll
      for (int j = 0; j < 4; ++j)
#pragma unroll
        for (int r = 0; r < 4; ++r)
          C[(size_t)(rb + i * 16 + r) * 1024 + cb + j * 16] = __float2bfloat16(acc[i][j][r]);
  }
}

// output projection: grid (8, 64), fp32 out
__global__ __launch_bounds__(256) void gemm_proj(const bf16* __restrict__ y,
                                                 const bf16* __restrict__ wp,
                                                 float* __restrict__ outp) {
  __shared__ __align__(16) bf16 As[128 * 32];
  __shared__ __align__(16) bf16 Bs[128 * 32];
  f32x4 acc[4][4];
  gemm_core(y, wp, As, Bs, acc);
  const int tid = threadIdx.x, lane = tid & 63, l15 = lane & 15, quad = lane >> 4,
            wave = tid >> 6;
  const int wm = (wave >> 1) * 64, wn = (wave & 1) * 64;
  const int rb = blockIdx.y * 128 + wm + quad * 4;
  const int cb = blockIdx.x * 128 + wn + l15;
#pragma unroll
  for (int i = 0; i < 4; ++i)
#pragma unroll
    for (int j = 0; j < 4; ++j)
#pragma unroll
      for (int r = 0; r < 4; ++r)
        outp[(size_t)(rb + i * 16 + r) * 1024 + cb + j * 16] = acc[i][j][r];
}

// ----------------------------------------------------------- flash attention
// grid (64 bh, 16 p): bh varies fastest so each CU's share mixes p values.
// Block p handles q-tiles p and 31-p; 32-key double-buffered K/V tiles.
//
// v2 changes (this round):
//  * QK^T computed SWAPPED: st = mfma(K_frag, Q_frag) -> S^T, lane holds
//    col q = l15, rows k = j*16 + quad*4 + r. The 4 P-values per j are
//    k-consecutive -> pack via v_cvt_pk_bf16_f32 and store P with ONE
//    ds_write_b64 per j (was 8 scalar ds_write_b16). PV read unchanged.
//  * softmax scale folded into Wq at cvt time (no per-element v_mul here).
//  * K/V LDS tiles XOR-swizzled (rule #21: linear global_load_lds dest +
//    inverse-permuted SOURCE column + same permutation on the READ):
//    dq ^= (row&3)^((row>>2)&3). Fragment reads drop 8-way -> 2-way bank
//    conflict (2-way is free, m136).
__global__ __launch_bounds__(256) void attn(const bf16* __restrict__ qb,
                                            const bf16* __restrict__ kb,
                                            const bf16* __restrict__ vt,
                                            bf16* __restrict__ yb) {
  __shared__ __align__(16) bf16 Ks[2][2048];
  __shared__ __align__(16) bf16 Vs[2][2048];
  __shared__ __align__(16) bf16 Ps[4][32 * 40];
  const int tid = threadIdx.x;
  const int lane = tid & 63, l15 = lane & 15, quad = lane >> 4, wave = tid >> 6;
  const int p = blockIdx.y;
  const int bh = blockIdx.x;
  const int b = bh >> 4, h = bh & 15;
  const size_t rowbase = (size_t)b * 2048;
  const int cb = h * 64;

  const int tlo = p, thi = 31 - p;
  const int gq0[2] = {tlo * 64 + wave * 16, thi * 64 + wave * 16};

  short8 aq[2][2];
#pragma unroll
  for (int g = 0; g < 2; ++g) {
    const bf16* qp = qb + (rowbase + gq0[g] + l15) * 1024 + cb + quad * 8;
    aq[g][0] = *reinterpret_cast<const short8*>(qp);
    aq[g][1] = *reinterpret_cast<const short8*>(qp + 32);
  }

  short8 ones;
#pragma unroll
  for (int i = 0; i < 8; ++i) ones[i] = (short)0x3F80;  // bf16 1.0

  f32x4 o[2][4], l4[2];
  const f32x4 zero = {0.f, 0.f, 0.f, 0.f};
#pragma unroll
  for (int g = 0; g < 2; ++g) {
#pragma unroll
    for (int dt = 0; dt < 4; ++dt) o[g][dt] = zero;
    l4[g] = zero;
  }

  // staging-side column swizzle: lane tid stages LDS slot (row(tid), dq(tid));
  // it must FETCH global column dq ^ f(row), f(row) = (row&3)^((row>>2)&3).
  // For both K (row = (tid&127)>>2) and V (row = tid>>2) the row bits are
  // tid[3:2] and tid[5:4], so one formula serves both.
  const int sdq = (((tid & 3) ^ ((tid >> 2) & 3) ^ ((tid >> 4) & 3))) * 8;
  const bf16* kg = kb + (rowbase + ((tid & 127) >> 2)) * 1024 + cb + (tid >> 7) * 32 + sdq;
  const bf16* vg = vt + ((size_t)bh * 64 + (tid >> 2)) * 2048 + sdq;
  bf16* Psw = &Ps[wave][0];
  // read-side column swizzle: fragment row is (j|dt)*16 + l15 -> row&3 = l15&3,
  // (row>>2)&3 = (l15>>2)&3.
  const int csw = (quad ^ (l15 & 3) ^ ((l15 >> 2) & 3)) * 8;

  const int nkt = 2 * thi + 2;
  async_copy16(kg, &Ks[0][tid * 8]);
  async_copy16(vg, &Vs[0][tid * 8]);

  for (int kt = 0; kt < nkt; ++kt) {
    const int buf = kt & 1;
    __syncthreads();  // tile kt resident; prior reads of buf^1 done
    if (kt + 1 < nkt) {
      async_copy16(kg + (size_t)(kt + 1) * 32 * 1024, &Ks[buf ^ 1][tid * 8]);
      async_copy16(vg + (kt + 1) * 32, &Vs[buf ^ 1][tid * 8]);
    }
    const int k0g = kt * 32;
    if (k0g > gq0[1] + 15) continue;

    short8 bk[2][2];
#pragma unroll
    for (int j = 0; j < 2; ++j)
#pragma unroll
      for (int ks = 0; ks < 2; ++ks)
        bk[j][ks] = *reinterpret_cast<const short8*>(
            &Ks[buf][ks * 1024 + (j * 16 + l15) * 32 + csw]);
    // V^T fragments (A-operand for PV)
    short8 av[4];
#pragma unroll
    for (int dt = 0; dt < 4; ++dt)
      av[dt] = *reinterpret_cast<const short8*>(&Vs[buf][(dt * 16 + l15) * 32 + csw]);

#pragma unroll
    for (int g = 0; g < 2; ++g) {
      if (k0g > gq0[g] + 15) continue;
      // swapped QK^T: st = K*Q^T = S^T. col = q = l15, row = k = j*16+quad*4+r.
      f32x4 st[2];
#pragma unroll
      for (int j = 0; j < 2; ++j) {
        st[j] = MFMA_BF16(bk[j][0], aq[g][0], zero);
        st[j] = MFMA_BF16(bk[j][1], aq[g][1], st[j]);
      }
      const bool need_mask = (k0g + 31 > gq0[g]);
#pragma unroll
      for (int j = 0; j < 2; ++j) {
        float pw[4];
#pragma unroll
        for (int r = 0; r < 4; ++r) {
          float val = st[j][r];  // already scaled (folded into Wq)
          if (need_mask && (k0g + j * 16 + quad * 4 + r) > (gq0[g] + l15))
            val = -INFINITY;
          pw[r] = __builtin_amdgcn_exp2f(val);
        }
        // P[q][k], q-row = g*16+l15, k-cols j*16+quad*4 .. +3 packed in 8B
        uint2 w;
        w.x = cvt_pk_bf16(pw[0], pw[1]);
        w.y = cvt_pk_bf16(pw[2], pw[3]);
        *reinterpret_cast<uint2*>(Psw + (g * 16 + l15) * 40 + j * 16 + quad * 4) = w;
      }
    }

    asm volatile("s_waitcnt lgkmcnt(0)" ::: "memory");

#pragma unroll
    for (int g = 0; g < 2; ++g) {
      if (k0g > gq0[g] + 15) continue;
      // P as B-fragment: O^T = V^T * P^T
      const short8 bp =
          *reinterpret_cast<const short8*>(Psw + (g * 16 + l15) * 40 + quad * 8);
#pragma unroll
      for (int dt = 0; dt < 4; ++dt) o[g][dt] = MFMA_BF16(av[dt], bp, o[g][dt]);
      l4[g] = MFMA_BF16(ones, bp, l4[g]);  // col-sums of P^T = row sums of P
    }
  }

  // epilogue: lane holds q = gq0[g]+l15, d = dt*16 + quad*4 + r (r contiguous)
#pragma unroll
  for (int g = 0; g < 2; ++g) {
    const float invl = 1.f / l4[g][0];
    bf16* yp = yb + (rowbase + gq0[g] + l15) * 1024 + cb + quad * 4;
#pragma unroll
    for (int dt = 0; dt < 4; ++dt) {
      ushort4 pk;
      pk.x = f2bf_bits(o[g][dt][0] * invl);
      pk.y = f2bf_bits(o[g][dt][1] * invl);
      pk.z = f2bf_bits(o[g][dt][2] * invl);
      pk.w = f2bf_bits(o[g][dt][3] * invl);
      *reinterpret_cast<ushort4*>(&yp[dt * 16]) = pk;
    }
  }
}

// ---------------------------------------------------------------------- launch
extern "C" void kernel_launch(void* const* d_in, const int* in_sizes, int n_in,
                              void* d_out, int out_size, void* d_ws, size_t ws_size,
                              hipStream_t stream) {
  const float* x = (const float*)d_in[0];
  const float* Wq = (const float*)d_in[1];
  const float* Wk = (const float*)d_in[2];
  const float* Wv = (const float*)d_in[3];
  const float* Wp = (const float*)d_in[4];
  float* out = (float*)d_out;

  const size_t MB = 1024 * 1024;
  char* ws = (char*)d_ws;
  bf16* xb = (bf16*)(ws);             // 16 MB; reused as yb after QKV
  bf16* qb = (bf16*)(ws + 16 * MB);   // 16 MB
  bf16* kb = (bf16*)(ws + 32 * MB);   // 16 MB
  bf16* vtb = (bf16*)(ws + 48 * MB);  // 16 MB, V transposed [bh][d][t]
  bf16* wqb = (bf16*)(ws + 64 * MB);  // 2 MB each
  bf16* wkb = (bf16*)(ws + 66 * MB);
  bf16* wvb = (bf16*)(ws + 68 * MB);
  bf16* wpb = (bf16*)(ws + 70 * MB);
  bf16* yb = xb;

  cvt_all<<<12288, 256, 0, stream>>>(x, Wq, Wk, Wv, Wp, xb, wqb, wkb, wvb, wpb);
  gemm_qkv<<<dim3(8, 64, 3), 256, 0, stream>>>(xb, wqb, wkb, wvb, qb, kb, vtb);
  attn<<<dim3(64, 16), 256, 0, stream>>>(qb, kb, vtb, yb);
  gemm_proj<<<dim3(8, 64), 256, 0, stream>>>(yb, wpb, out);
}

// Round 2
// 280.545 us; speedup vs baseline: 1.0684x; 1.0362x over previous
//
#include <hip/hip_runtime.h>
#include <hip/hip_bf16.h>
#include <math.h>

typedef __hip_bfloat16 bf16;
typedef __attribute__((ext_vector_type(8))) short short8;
typedef __attribute__((ext_vector_type(4))) float f32x4;
typedef __attribute__((ext_vector_type(2))) unsigned uint2v;
typedef __attribute__((ext_vector_type(4))) unsigned uint4v;

#define MFMA_BF16(a, b, c) __builtin_amdgcn_mfma_f32_16x16x32_bf16((a), (b), (c), 0, 0, 0)

// async global->LDS, 16B per lane (m97 pattern). LDS dest must be base + lane*16.
__device__ __forceinline__ void async_copy16(const bf16* g, bf16* l) {
  __builtin_amdgcn_global_load_lds(
      (const __attribute__((address_space(1))) void*)g,
      (__attribute__((address_space(3))) void*)l,
      16, 0, 0);
}

__device__ __forceinline__ unsigned short f2bf_bits(float f) {
  bf16 h = __float2bfloat16(f);
  return *reinterpret_cast<unsigned short*>(&h);
}

// pack 2 f32 -> 2 bf16 in one u32 (lo = first arg). No builtin on gfx950 (m240).
__device__ __forceinline__ unsigned cvt_pk_bf16(float lo, float hi) {
  unsigned r;
  asm("v_cvt_pk_bf16_f32 %0, %1, %2" : "=v"(r) : "v"(lo), "v"(hi));
  return r;
}

// ------------------------------------------- all fp32 -> bf16 in one launch
// blocks [0,8192): x ; [8192,9216): Wq (pre-scaled by 0.125*log2e so softmax
// scale is folded into the Q projection) ; [9216,10240): Wk ; [10240,11264): Wv ;
// [11264,12288): Wp. One float4 per thread.
__global__ __launch_bounds__(256) void cvt_all(const float* __restrict__ x,
                                               const float* __restrict__ wq,
                                               const float* __restrict__ wk,
                                               const float* __restrict__ wv,
                                               const float* __restrict__ wp,
                                               bf16* __restrict__ xb, bf16* __restrict__ wqb,
                                               bf16* __restrict__ wkb, bf16* __restrict__ wvb,
                                               bf16* __restrict__ wpb) {
  const int bid = blockIdx.x;
  const float* in;
  bf16* out;
  int off;
  float scale = 1.0f;
  if (bid < 8192) {
    in = x; out = xb; off = bid;
  } else if (bid < 9216) {
    in = wq; out = wqb; off = bid - 8192;
    scale = 0.180336880111112f;  // 0.125 * log2(e)
  } else if (bid < 10240) {
    in = wk; out = wkb; off = bid - 9216;
  } else if (bid < 11264) {
    in = wv; out = wvb; off = bid - 10240;
  } else {
    in = wp; out = wpb; off = bid - 11264;
  }
  const int i = off * 256 + threadIdx.x;
  float4 v = reinterpret_cast<const float4*>(in)[i];
  ushort4 u;
  u.x = f2bf_bits(v.x * scale);
  u.y = f2bf_bits(v.y * scale);
  u.z = f2bf_bits(v.z * scale);
  u.w = f2bf_bits(v.w * scale);
  reinterpret_cast<ushort4*>(out)[i] = u;
}

// ------------------------------------------------- 128x128 GEMM core (C = A*W^T)
__device__ __forceinline__ void gemm_core(const bf16* __restrict__ A,
                                          const bf16* __restrict__ W,
                                          bf16* As, bf16* Bs, f32x4 (&acc)[4][4]) {
  const int tid = threadIdx.x;
  const int lane = tid & 63;
  const int l15 = lane & 15;
  const int quad = lane >> 4;
  const int wave = tid >> 6;
  const int wm = (wave >> 1) * 64;
  const int wn = (wave & 1) * 64;
  const int K = 1024;

  const f32x4 zero = {0.f, 0.f, 0.f, 0.f};
#pragma unroll
  for (int i = 0; i < 4; ++i)
#pragma unroll
    for (int j = 0; j < 4; ++j) acc[i][j] = zero;

  const int srow = tid >> 2;
  const int scol = (tid & 3) * 8;
  const bf16* ga = A + (size_t)(blockIdx.y * 128 + srow) * K + scol;
  const bf16* gb = W + (size_t)(blockIdx.x * 128 + srow) * K + scol;
  bf16* lA = As + tid * 8;
  bf16* lB = Bs + tid * 8;

  for (int kt = 0; kt < 32; ++kt) {
    const int k0 = kt * 32;
    async_copy16(ga + k0, lA);
    async_copy16(ga + k0 + 64 * K, lA + 2048);
    async_copy16(gb + k0, lB);
    async_copy16(gb + k0 + 64 * K, lB + 2048);
    __syncthreads();
    short8 afr[4], bfr[4];
#pragma unroll
    for (int i = 0; i < 4; ++i)
      afr[i] = *reinterpret_cast<const short8*>(As + (wm + i * 16 + l15) * 32 + quad * 8);
#pragma unroll
    for (int j = 0; j < 4; ++j)
      bfr[j] = *reinterpret_cast<const short8*>(Bs + (wn + j * 16 + l15) * 32 + quad * 8);
#pragma unroll
    for (int i = 0; i < 4; ++i)
#pragma unroll
      for (int j = 0; j < 4; ++j) acc[i][j] = MFMA_BF16(afr[i], bfr[j], acc[i][j]);
    __syncthreads();
  }
}

// fused q/k/v projection: grid (8, 64, 3). z==2 (V) writes TRANSPOSED into
// vt[(b*1024 + col)*2048 + tau(t)] (i.e. [bh][d][t], with t's bits 2,3 swapped
// inside each 32-key block). tau matches the k-permutation pi that the attn
// kernel's permlane32_swap P-redistribution induces on the PV contraction
// index, so PV contracts V and P over the SAME key order.
__global__ __launch_bounds__(256) void gemm_qkv(const bf16* __restrict__ x,
                                                const bf16* __restrict__ wq,
                                                const bf16* __restrict__ wk,
                                                const bf16* __restrict__ wv,
                                                bf16* __restrict__ q, bf16* __restrict__ k,
                                                bf16* __restrict__ vt) {
  __shared__ __align__(16) bf16 As[128 * 32];
  __shared__ __align__(16) bf16 Bs[128 * 32];
  const bf16* W = (blockIdx.z == 0) ? wq : (blockIdx.z == 1) ? wk : wv;
  f32x4 acc[4][4];
  gemm_core(x, W, As, Bs, acc);
  const int tid = threadIdx.x, lane = tid & 63, l15 = lane & 15, quad = lane >> 4,
            wave = tid >> 6;
  const int wm = (wave >> 1) * 64, wn = (wave & 1) * 64;
  const int rb = blockIdx.y * 128 + wm + quad * 4;
  const int cb = blockIdx.x * 128 + wn + l15;
  if (blockIdx.z == 2) {
#pragma unroll
    for (int i = 0; i < 4; ++i)
#pragma unroll
      for (int j = 0; j < 4; ++j) {
        const int tg = rb + i * 16;
        const int col = cb + j * 16;
        const int b = tg >> 11, tl = tg & 2047;
        // tau: swap bits 2 and 3 of t (4-aligned store -> pure chunk move)
        const int tls = (tl & ~12) | ((tl & 4) << 1) | ((tl & 8) >> 1);
        ushort4 pk;
        pk.x = f2bf_bits(acc[i][j][0]);
        pk.y = f2bf_bits(acc[i][j][1]);
        pk.z = f2bf_bits(acc[i][j][2]);
        pk.w = f2bf_bits(acc[i][j][3]);
        *reinterpret_cast<ushort4*>(&vt[((size_t)(b * 1024 + col)) * 2048 + tls]) = pk;
      }
  } else {
    bf16* C = (blockIdx.z == 0) ? q : k;
#pragma unroll
    for (int i = 0; i < 4; ++i)
#pragma unroll
      for (int j = 0; j < 4; ++j)
#pragma unroll
        for (int r = 0; r < 4; ++r)
          C[(size_t)(rb + i * 16 + r) * 1024 + cb + j * 16] = __float2bfloat16(acc[i][j][r]);
  }
}

// output projection: grid (8, 64), fp32 out
__global__ __launch_bounds__(256) void gemm_proj(const bf16* __restrict__ y,
                                                 const bf16* __restrict__ wp,
                                                 float* __restrict__ outp) {
  __shared__ __align__(16) bf16 As[128 * 32];
  __shared__ __align__(16) bf16 Bs[128 * 32];
  f32x4 acc[4][4];
  gemm_core(y, wp, As, Bs, acc);
  const int tid = threadIdx.x, lane = tid & 63, l15 = lane & 15, quad = lane >> 4,
            wave = tid >> 6;
  const int wm = (wave >> 1) * 64, wn = (wave & 1) * 64;
  const int rb = blockIdx.y * 128 + wm + quad * 4;
  const int cb = blockIdx.x * 128 + wn + l15;
#pragma unroll
  for (int i = 0; i < 4; ++i)
#pragma unroll
    for (int j = 0; j < 4; ++j)
#pragma unroll
      for (int r = 0; r < 4; ++r)
        outp[(size_t)(rb + i * 16 + r) * 1024 + cb + j * 16] = acc[i][j][r];
}

// ----------------------------------------------------------- flash attention
// grid (64 bh, 16 p): bh varies fastest so each CU's share mixes p values.
// Block p handles q-tiles p and 31-p; 32-key double-buffered K/V tiles.
//
// v3 changes (this round): P never touches LDS.
//  * swapped QK^T leaves S^T[k][q] in registers (lane: q=l15, k=j*16+quad*4+r).
//  * after mask/exp2, 4x v_cvt_pk_bf16_f32 + 2x permlane32_swap redistribute
//    the 16 P-values into a valid PV B-fragment, up to the fixed k-permutation
//    pi(kB) = swap bits 2,3 of kB. pi is baked into vt's t-order (tau in
//    gemm_qkv), so av fragments line up with no extra LDS traffic.
//  * Ps buffer, P ds_writes/ds_reads and the lgkmcnt serialization are gone
//    (LDS 26624 -> 16384 B).
__global__ __launch_bounds__(256) void attn(const bf16* __restrict__ qb,
                                            const bf16* __restrict__ kb,
                                            const bf16* __restrict__ vt,
                                            bf16* __restrict__ yb) {
  __shared__ __align__(16) bf16 Ks[2][2048];
  __shared__ __align__(16) bf16 Vs[2][2048];
  const int tid = threadIdx.x;
  const int lane = tid & 63, l15 = lane & 15, quad = lane >> 4, wave = tid >> 6;
  const int p = blockIdx.y;
  const int bh = blockIdx.x;
  const int b = bh >> 4, h = bh & 15;
  const size_t rowbase = (size_t)b * 2048;
  const int cb = h * 64;

  const int tlo = p, thi = 31 - p;
  const int gq0[2] = {tlo * 64 + wave * 16, thi * 64 + wave * 16};

  short8 aq[2][2];
#pragma unroll
  for (int g = 0; g < 2; ++g) {
    const bf16* qp = qb + (rowbase + gq0[g] + l15) * 1024 + cb + quad * 8;
    aq[g][0] = *reinterpret_cast<const short8*>(qp);
    aq[g][1] = *reinterpret_cast<const short8*>(qp + 32);
  }

  short8 ones;
#pragma unroll
  for (int i = 0; i < 8; ++i) ones[i] = (short)0x3F80;  // bf16 1.0

  f32x4 o[2][4], l4[2];
  const f32x4 zero = {0.f, 0.f, 0.f, 0.f};
#pragma unroll
  for (int g = 0; g < 2; ++g) {
#pragma unroll
    for (int dt = 0; dt < 4; ++dt) o[g][dt] = zero;
    l4[g] = zero;
  }

  // staging-side column swizzle: lane tid stages LDS slot (row(tid), dq(tid));
  // it must FETCH global column dq ^ f(row), f(row) = (row&3)^((row>>2)&3).
  // For both K (row = (tid&127)>>2) and V (row = tid>>2) the row bits are
  // tid[3:2] and tid[5:4], so one formula serves both.
  const int sdq = (((tid & 3) ^ ((tid >> 2) & 3) ^ ((tid >> 4) & 3))) * 8;
  const bf16* kg = kb + (rowbase + ((tid & 127) >> 2)) * 1024 + cb + (tid >> 7) * 32 + sdq;
  const bf16* vg = vt + ((size_t)bh * 64 + (tid >> 2)) * 2048 + sdq;
  // read-side column swizzle: fragment row is (j|dt)*16 + l15 -> row&3 = l15&3,
  // (row>>2)&3 = (l15>>2)&3.
  const int csw = (quad ^ (l15 & 3) ^ ((l15 >> 2) & 3)) * 8;

  const int nkt = 2 * thi + 2;
  async_copy16(kg, &Ks[0][tid * 8]);
  async_copy16(vg, &Vs[0][tid * 8]);

  for (int kt = 0; kt < nkt; ++kt) {
    const int buf = kt & 1;
    __syncthreads();  // tile kt resident; prior reads of buf^1 done
    if (kt + 1 < nkt) {
      async_copy16(kg + (size_t)(kt + 1) * 32 * 1024, &Ks[buf ^ 1][tid * 8]);
      async_copy16(vg + (kt + 1) * 32, &Vs[buf ^ 1][tid * 8]);
    }
    const int k0g = kt * 32;
    if (k0g > gq0[1] + 15) continue;

    short8 bk[2][2];
#pragma unroll
    for (int j = 0; j < 2; ++j)
#pragma unroll
      for (int ks = 0; ks < 2; ++ks)
        bk[j][ks] = *reinterpret_cast<const short8*>(
            &Ks[buf][ks * 1024 + (j * 16 + l15) * 32 + csw]);
    // V^T fragments (A-operand for PV); vt's tau-order makes reg e hold
    // V[t = k0g + pi(quad*8+e)][d].
    short8 av[4];
#pragma unroll
    for (int dt = 0; dt < 4; ++dt)
      av[dt] = *reinterpret_cast<const short8*>(&Vs[buf][(dt * 16 + l15) * 32 + csw]);

#pragma unroll
    for (int g = 0; g < 2; ++g) {
      if (k0g > gq0[g] + 15) continue;
      // swapped QK^T: st = K*Q^T = S^T. col = q = l15, row = k = j*16+quad*4+r.
      f32x4 st[2];
#pragma unroll
      for (int j = 0; j < 2; ++j) {
        st[j] = MFMA_BF16(bk[j][0], aq[g][0], zero);
        st[j] = MFMA_BF16(bk[j][1], aq[g][1], st[j]);
      }
      const bool need_mask = (k0g + 31 > gq0[g]);
      unsigned w[2][2];  // [j][h]: packed bf16 pair, k = j*16+quad*4+2h{,+1}
#pragma unroll
      for (int j = 0; j < 2; ++j) {
        float pw[4];
#pragma unroll
        for (int r = 0; r < 4; ++r) {
          float val = st[j][r];  // already scaled (folded into Wq)
          if (need_mask && (k0g + j * 16 + quad * 4 + r) > (gq0[g] + l15))
            val = -INFINITY;
          pw[r] = __builtin_amdgcn_exp2f(val);
        }
        w[j][0] = cvt_pk_bf16(pw[0], pw[1]);
        w[j][1] = cvt_pk_bf16(pw[2], pw[3]);
      }
      // permlane32_swap redistributes so lane(quad) holds kB = quad*8+e with
      // actual k = pi(kB) (bits 2,3 of kB swapped) -- matches vt's tau-order.
      uint2v s0 = __builtin_amdgcn_permlane32_swap(w[0][0], w[1][0], false, false);
      uint2v s1 = __builtin_amdgcn_permlane32_swap(w[0][1], w[1][1], false, false);
      uint4v u;
      u[0] = s0[0];  // kp slots e2=0: A[h=0]
      u[1] = s1[0];  // e2=1: A[h=1]
      u[2] = s0[1];  // e2=2: B[h=0]
      u[3] = s1[1];  // e2=3: B[h=1]
      const short8 bp = __builtin_bit_cast(short8, u);
#pragma unroll
      for (int dt = 0; dt < 4; ++dt) o[g][dt] = MFMA_BF16(av[dt], bp, o[g][dt]);
      l4[g] = MFMA_BF16(ones, bp, l4[g]);  // row sums of P (pi-invariant)
    }
  }

  // epilogue: lane holds q = gq0[g]+l15, d = dt*16 + quad*4 + r (r contiguous)
#pragma unroll
  for (int g = 0; g < 2; ++g) {
    const float invl = 1.f / l4[g][0];
    bf16* yp = yb + (rowbase + gq0[g] + l15) * 1024 + cb + quad * 4;
#pragma unroll
    for (int dt = 0; dt < 4; ++dt) {
      ushort4 pk;
      pk.x = f2bf_bits(o[g][dt][0] * invl);
      pk.y = f2bf_bits(o[g][dt][1] * invl);
      pk.z = f2bf_bits(o[g][dt][2] * invl);
      pk.w = f2bf_bits(o[g][dt][3] * invl);
      *reinterpret_cast<ushort4*>(&yp[dt * 16]) = pk;
    }
  }
}

// ---------------------------------------------------------------------- launch
extern "C" void kernel_launch(void* const* d_in, const int* in_sizes, int n_in,
                              void* d_out, int out_size, void* d_ws, size_t ws_size,
                              hipStream_t stream) {
  const float* x = (const float*)d_in[0];
  const float* Wq = (const float*)d_in[1];
  const float* Wk = (const float*)d_in[2];
  const float* Wv = (const float*)d_in[3];
  const float* Wp = (const float*)d_in[4];
  float* out = (float*)d_out;

  const size_t MB = 1024 * 1024;
  char* ws = (char*)d_ws;
  bf16* xb = (bf16*)(ws);             // 16 MB; reused as yb after QKV
  bf16* qb = (bf16*)(ws + 16 * MB);   // 16 MB
  bf16* kb = (bf16*)(ws + 32 * MB);   // 16 MB
  bf16* vtb = (bf16*)(ws + 48 * MB);  // 16 MB, V transposed [bh][d][tau(t)]
  bf16* wqb = (bf16*)(ws + 64 * MB);  // 2 MB each
  bf16* wkb = (bf16*)(ws + 66 * MB);
  bf16* wvb = (bf16*)(ws + 68 * MB);
  bf16* wpb = (bf16*)(ws + 70 * MB);
  bf16* yb = xb;

  cvt_all<<<12288, 256, 0, stream>>>(x, Wq, Wk, Wv, Wp, xb, wqb, wkb, wvb, wpb);
  gemm_qkv<<<dim3(8, 64, 3), 256, 0, stream>>>(xb, wqb, wkb, wvb, qb, kb, vtb);
  attn<<<dim3(64, 16), 256, 0, stream>>>(qb, kb, vtb, yb);
  gemm_proj<<<dim3(8, 64), 256, 0, stream>>>(yb, wpb, out);
}

// Round 3
// 277.761 us; speedup vs baseline: 1.0791x; 1.0100x over previous
//
#include <hip/hip_runtime.h>
#include <hip/hip_bf16.h>
#include <math.h>

typedef __hip_bfloat16 bf16;
typedef __attribute__((ext_vector_type(8))) short short8;
typedef __attribute__((ext_vector_type(4))) float f32x4;
typedef __attribute__((ext_vector_type(2))) unsigned uint2v;
typedef __attribute__((ext_vector_type(4))) unsigned uint4v;

#define MFMA_BF16(a, b, c) __builtin_amdgcn_mfma_f32_16x16x32_bf16((a), (b), (c), 0, 0, 0)

// async global->LDS, 16B per lane (m97 pattern). LDS dest must be base + lane*16.
__device__ __forceinline__ void async_copy16(const bf16* g, bf16* l) {
  __builtin_amdgcn_global_load_lds(
      (const __attribute__((address_space(1))) void*)g,
      (__attribute__((address_space(3))) void*)l,
      16, 0, 0);
}

__device__ __forceinline__ unsigned short f2bf_bits(float f) {
  bf16 h = __float2bfloat16(f);
  return *reinterpret_cast<unsigned short*>(&h);
}

// pack 2 f32 -> 2 bf16 in one u32 (lo = first arg). No builtin on gfx950 (m240).
__device__ __forceinline__ unsigned cvt_pk_bf16(float lo, float hi) {
  unsigned r;
  asm("v_cvt_pk_bf16_f32 %0, %1, %2" : "=v"(r) : "v"(lo), "v"(hi));
  return r;
}

// ------------------------------------------- all fp32 -> bf16 in one launch
__global__ __launch_bounds__(256) void cvt_all(const float* __restrict__ x,
                                               const float* __restrict__ wq,
                                               const float* __restrict__ wk,
                                               const float* __restrict__ wv,
                                               const float* __restrict__ wp,
                                               bf16* __restrict__ xb, bf16* __restrict__ wqb,
                                               bf16* __restrict__ wkb, bf16* __restrict__ wvb,
                                               bf16* __restrict__ wpb) {
  const int bid = blockIdx.x;
  const float* in;
  bf16* out;
  int off;
  float scale = 1.0f;
  if (bid < 8192) {
    in = x; out = xb; off = bid;
  } else if (bid < 9216) {
    in = wq; out = wqb; off = bid - 8192;
    scale = 0.180336880111112f;  // 0.125 * log2(e) folded into Wq
  } else if (bid < 10240) {
    in = wk; out = wkb; off = bid - 9216;
  } else if (bid < 11264) {
    in = wv; out = wvb; off = bid - 10240;
  } else {
    in = wp; out = wpb; off = bid - 11264;
  }
  const int i = off * 256 + threadIdx.x;
  float4 v = reinterpret_cast<const float4*>(in)[i];
  ushort4 u;
  u.x = f2bf_bits(v.x * scale);
  u.y = f2bf_bits(v.y * scale);
  u.z = f2bf_bits(v.z * scale);
  u.w = f2bf_bits(v.w * scale);
  reinterpret_cast<ushort4*>(out)[i] = u;
}

// --------------------------- 256x128 phase-pipelined GEMM core (C = A*W^T)
// T2+T3+T4+T5 structure, derived fresh (race-ledger in journal):
//  * BK=32; 4 LDS K-tile buffers (4 x (A 16KB + B 8KB) = 96KB). Tile T is read
//    from buf T&3; phase T stages tile T+3 into buf (T+3)&3 = (T-1)&3, whose
//    reads all finished before T-1's trailing barrier (each wave does
//    lgkmcnt(0) before its MFMAs, hence before that barrier).
//  * counted vmcnt: 3 loads/tile, 2 tiles in flight -> vmcnt(6) per phase
//    (never a drain-0 in steady state; tail 6->3->0). Cover invariant: at
//    phase T's vmcnt(6), all staging through tile T+1 has landed -- exactly
//    what phase T+1 reads after the barrier.
//  * LDS XOR swizzle for 64B rows: chunk ^= (row>>1)&3. Each 8-lane octet of a
//    ds_read_b128 hits 8 distinct 16B slots (enumerated) -> conflict-free.
//    Rule 21: linear global_load_lds dest + inverse-swizzled global source +
//    same involution on the read.
//  * raw s_barrier (NOT __syncthreads -- that drains vmcnt(0) and kills the
//    pipeline); lgkmcnt(0)+sched_barrier(0) before MFMA cluster (rule 18);
//    setprio(1) around the 16-MFMA cluster (T5; pays with phase-split, m218b).
__device__ __forceinline__ void gemm_core256(const bf16* __restrict__ A,
                                             const bf16* __restrict__ W,
                                             f32x4 (&acc)[4][4]) {
  __shared__ __align__(16) bf16 L[4][12288];  // per buf: A[256*32] then B[128*32]
  const int t = threadIdx.x;
  const int lane = t & 63;
  const int l15 = lane & 15;
  const int quad = (lane >> 4) & 3;
  const int wave = t >> 6;
  const int wm = (wave >> 1) * 64;   // 4 M-groups of 64 rows
  const int wn = (wave & 1) * 64;    // 2 N-groups of 64 cols
  const int K = 1024;

  const f32x4 zero = {0.f, 0.f, 0.f, 0.f};
#pragma unroll
  for (int m = 0; m < 4; ++m)
#pragma unroll
    for (int n = 0; n < 4; ++n) acc[m][n] = zero;

  // staging: thread t owns LDS slot (row=t>>2, chunk=t&3); with the swizzle
  // LDS[row][s] = global[row][s ^ f(row)], f(row)=(row>>1)&3, it must fetch
  // global chunk (t&3) ^ ((t>>3)&3). Rows +128 (A half 1) keep the same f bits.
  const int srow = t >> 2;
  const int schunk = ((t & 3) ^ ((t >> 3) & 3)) * 8;
  const bf16* ga0 = A + (size_t)(blockIdx.y * 256 + srow) * K + schunk;
  const bf16* ga1 = ga0 + (size_t)128 * K;
  const bf16* gb0 = W + (size_t)(blockIdx.x * 128 + srow) * K + schunk;

  // fragment reads: row = w? + {m,n}*16 + l15 -> f(row) = (l15>>1)&3
  const int fsw = (quad ^ ((l15 >> 1) & 3)) * 8;
  const int arow = (wm + l15) * 32 + fsw;         // + m*512
  const int brow = 8192 + (wn + l15) * 32 + fsw;  // + n*512

  // prologue: stage tiles 0,1,2; vmcnt(6) -> tile 0 landed (9-6=3 loads)
#pragma unroll
  for (int kt = 0; kt < 3; ++kt) {
    bf16* Ld = &L[kt][0];
    async_copy16(ga0 + kt * 32, Ld + t * 8);
    async_copy16(ga1 + kt * 32, Ld + 4096 + t * 8);
    async_copy16(gb0 + kt * 32, Ld + 8192 + t * 8);
  }
  asm volatile("s_waitcnt vmcnt(6)" ::: "memory");
  __builtin_amdgcn_s_barrier();

  for (int T = 0; T < 32; ++T) {
    const bf16* Lb = &L[T & 3][0];
    short8 af[4], bfr[4];
#pragma unroll
    for (int m = 0; m < 4; ++m)
      af[m] = *reinterpret_cast<const short8*>(Lb + arow + m * 512);
#pragma unroll
    for (int n = 0; n < 4; ++n)
      bfr[n] = *reinterpret_cast<const short8*>(Lb + brow + n * 512);
    if (T <= 28) {
      bf16* Ld = &L[(T + 3) & 3][0];
      async_copy16(ga0 + (T + 3) * 32, Ld + t * 8);
      async_copy16(ga1 + (T + 3) * 32, Ld + 4096 + t * 8);
      async_copy16(gb0 + (T + 3) * 32, Ld + 8192 + t * 8);
    }
    if (T < 29)
      asm volatile("s_waitcnt vmcnt(6)" ::: "memory");
    else if (T == 29)
      asm volatile("s_waitcnt vmcnt(3)" ::: "memory");
    else
      asm volatile("s_waitcnt vmcnt(0)" ::: "memory");
    __builtin_amdgcn_s_barrier();
    asm volatile("s_waitcnt lgkmcnt(0)" ::: "memory");
    __builtin_amdgcn_sched_barrier(0);
    __builtin_amdgcn_s_setprio(1);
#pragma unroll
    for (int m = 0; m < 4; ++m)
#pragma unroll
      for (int n = 0; n < 4; ++n) acc[m][n] = MFMA_BF16(af[m], bfr[n], acc[m][n]);
    __builtin_amdgcn_s_setprio(0);
    __builtin_amdgcn_sched_barrier(0);
    __builtin_amdgcn_s_barrier();
  }
}

// fused q/k/v projection: grid (8, 32, 3), 512 threads. z==2 (V) writes
// TRANSPOSED into vt[(b*1024 + col)*2048 + tau(t)] ([bh][d][t], t bits 2,3
// swapped inside each 32-key block -- matches attn's permlane k-permutation).
__global__ __launch_bounds__(512, 2) void gemm_qkv(const bf16* __restrict__ x,
                                                   const bf16* __restrict__ wq,
                                                   const bf16* __restrict__ wk,
                                                   const bf16* __restrict__ wv,
                                                   bf16* __restrict__ q, bf16* __restrict__ k,
                                                   bf16* __restrict__ vt) {
  const bf16* W = (blockIdx.z == 0) ? wq : (blockIdx.z == 1) ? wk : wv;
  f32x4 acc[4][4];
  gemm_core256(x, W, acc);
  const int t = threadIdx.x, lane = t & 63, l15 = lane & 15, quad = (lane >> 4) & 3,
            wave = t >> 6;
  const int wm = (wave >> 1) * 64, wn = (wave & 1) * 64;
  const int rb = blockIdx.y * 256 + wm + quad * 4;
  const int cbb = blockIdx.x * 128 + wn + l15;
  if (blockIdx.z == 2) {
#pragma unroll
    for (int m = 0; m < 4; ++m)
#pragma unroll
      for (int n = 0; n < 4; ++n) {
        const int tg = rb + m * 16;
        const int col = cbb + n * 16;
        const int b = tg >> 11, tl = tg & 2047;
        const int tls = (tl & ~12) | ((tl & 4) << 1) | ((tl & 8) >> 1);  // tau
        ushort4 pk;
        pk.x = f2bf_bits(acc[m][n][0]);
        pk.y = f2bf_bits(acc[m][n][1]);
        pk.z = f2bf_bits(acc[m][n][2]);
        pk.w = f2bf_bits(acc[m][n][3]);
        *reinterpret_cast<ushort4*>(&vt[((size_t)(b * 1024 + col)) * 2048 + tls]) = pk;
      }
  } else {
    bf16* C = (blockIdx.z == 0) ? q : k;
#pragma unroll
    for (int m = 0; m < 4; ++m)
#pragma unroll
      for (int n = 0; n < 4; ++n)
#pragma unroll
        for (int r = 0; r < 4; ++r)
          C[(size_t)(rb + m * 16 + r) * 1024 + cbb + n * 16] = __float2bfloat16(acc[m][n][r]);
  }
}

// output projection: grid (8, 32), 512 threads, fp32 out
__global__ __launch_bounds__(512, 2) void gemm_proj(const bf16* __restrict__ y,
                                                    const bf16* __restrict__ wp,
                                                    float* __restrict__ outp) {
  f32x4 acc[4][4];
  gemm_core256(y, wp, acc);
  const int t = threadIdx.x, lane = t & 63, l15 = lane & 15, quad = (lane >> 4) & 3,
            wave = t >> 6;
  const int wm = (wave >> 1) * 64, wn = (wave & 1) * 64;
  const int rb = blockIdx.y * 256 + wm + quad * 4;
  const int cbb = blockIdx.x * 128 + wn + l15;
#pragma unroll
  for (int m = 0; m < 4; ++m)
#pragma unroll
    for (int n = 0; n < 4; ++n)
#pragma unroll
      for (int r = 0; r < 4; ++r)
        outp[(size_t)(rb + m * 16 + r) * 1024 + cbb + n * 16] = acc[m][n][r];
}

// ----------------------------------------------------------- flash attention
// (unchanged from R2 -- isolate the GEMM change this round)
__global__ __launch_bounds__(256) void attn(const bf16* __restrict__ qb,
                                            const bf16* __restrict__ kb,
                                            const bf16* __restrict__ vt,
                                            bf16* __restrict__ yb) {
  __shared__ __align__(16) bf16 Ks[2][2048];
  __shared__ __align__(16) bf16 Vs[2][2048];
  const int tid = threadIdx.x;
  const int lane = tid & 63, l15 = lane & 15, quad = lane >> 4, wave = tid >> 6;
  const int p = blockIdx.y;
  const int bh = blockIdx.x;
  const int b = bh >> 4, h = bh & 15;
  const size_t rowbase = (size_t)b * 2048;
  const int cb = h * 64;

  const int tlo = p, thi = 31 - p;
  const int gq0[2] = {tlo * 64 + wave * 16, thi * 64 + wave * 16};

  short8 aq[2][2];
#pragma unroll
  for (int g = 0; g < 2; ++g) {
    const bf16* qp = qb + (rowbase + gq0[g] + l15) * 1024 + cb + quad * 8;
    aq[g][0] = *reinterpret_cast<const short8*>(qp);
    aq[g][1] = *reinterpret_cast<const short8*>(qp + 32);
  }

  short8 ones;
#pragma unroll
  for (int i = 0; i < 8; ++i) ones[i] = (short)0x3F80;  // bf16 1.0

  f32x4 o[2][4], l4[2];
  const f32x4 zero = {0.f, 0.f, 0.f, 0.f};
#pragma unroll
  for (int g = 0; g < 2; ++g) {
#pragma unroll
    for (int dt = 0; dt < 4; ++dt) o[g][dt] = zero;
    l4[g] = zero;
  }

  const int sdq = (((tid & 3) ^ ((tid >> 2) & 3) ^ ((tid >> 4) & 3))) * 8;
  const bf16* kg = kb + (rowbase + ((tid & 127) >> 2)) * 1024 + cb + (tid >> 7) * 32 + sdq;
  const bf16* vg = vt + ((size_t)bh * 64 + (tid >> 2)) * 2048 + sdq;
  const int csw = (quad ^ (l15 & 3) ^ ((l15 >> 2) & 3)) * 8;

  const int nkt = 2 * thi + 2;
  async_copy16(kg, &Ks[0][tid * 8]);
  async_copy16(vg, &Vs[0][tid * 8]);

  for (int kt = 0; kt < nkt; ++kt) {
    const int buf = kt & 1;
    __syncthreads();  // tile kt resident; prior reads of buf^1 done
    if (kt + 1 < nkt) {
      async_copy16(kg + (size_t)(kt + 1) * 32 * 1024, &Ks[buf ^ 1][tid * 8]);
      async_copy16(vg + (kt + 1) * 32, &Vs[buf ^ 1][tid * 8]);
    }
    const int k0g = kt * 32;
    if (k0g > gq0[1] + 15) continue;

    short8 bk[2][2];
#pragma unroll
    for (int j = 0; j < 2; ++j)
#pragma unroll
      for (int ks = 0; ks < 2; ++ks)
        bk[j][ks] = *reinterpret_cast<const short8*>(
            &Ks[buf][ks * 1024 + (j * 16 + l15) * 32 + csw]);
    short8 av[4];
#pragma unroll
    for (int dt = 0; dt < 4; ++dt)
      av[dt] = *reinterpret_cast<const short8*>(&Vs[buf][(dt * 16 + l15) * 32 + csw]);

#pragma unroll
    for (int g = 0; g < 2; ++g) {
      if (k0g > gq0[g] + 15) continue;
      f32x4 st[2];
#pragma unroll
      for (int j = 0; j < 2; ++j) {
        st[j] = MFMA_BF16(bk[j][0], aq[g][0], zero);
        st[j] = MFMA_BF16(bk[j][1], aq[g][1], st[j]);
      }
      const bool need_mask = (k0g + 31 > gq0[g]);
      unsigned w[2][2];
#pragma unroll
      for (int j = 0; j < 2; ++j) {
        float pw[4];
#pragma unroll
        for (int r = 0; r < 4; ++r) {
          float val = st[j][r];
          if (need_mask && (k0g + j * 16 + quad * 4 + r) > (gq0[g] + l15))
            val = -INFINITY;
          pw[r] = __builtin_amdgcn_exp2f(val);
        }
        w[j][0] = cvt_pk_bf16(pw[0], pw[1]);
        w[j][1] = cvt_pk_bf16(pw[2], pw[3]);
      }
      uint2v s0 = __builtin_amdgcn_permlane32_swap(w[0][0], w[1][0], false, false);
      uint2v s1 = __builtin_amdgcn_permlane32_swap(w[0][1], w[1][1], false, false);
      uint4v u;
      u[0] = s0[0];
      u[1] = s1[0];
      u[2] = s0[1];
      u[3] = s1[1];
      const short8 bp = __builtin_bit_cast(short8, u);
#pragma unroll
      for (int dt = 0; dt < 4; ++dt) o[g][dt] = MFMA_BF16(av[dt], bp, o[g][dt]);
      l4[g] = MFMA_BF16(ones, bp, l4[g]);
    }
  }

#pragma unroll
  for (int g = 0; g < 2; ++g) {
    const float invl = 1.f / l4[g][0];
    bf16* yp = yb + (rowbase + gq0[g] + l15) * 1024 + cb + quad * 4;
#pragma unroll
    for (int dt = 0; dt < 4; ++dt) {
      ushort4 pk;
      pk.x = f2bf_bits(o[g][dt][0] * invl);
      pk.y = f2bf_bits(o[g][dt][1] * invl);
      pk.z = f2bf_bits(o[g][dt][2] * invl);
      pk.w = f2bf_bits(o[g][dt][3] * invl);
      *reinterpret_cast<ushort4*>(&yp[dt * 16]) = pk;
    }
  }
}

// ---------------------------------------------------------------------- launch
extern "C" void kernel_launch(void* const* d_in, const int* in_sizes, int n_in,
                              void* d_out, int out_size, void* d_ws, size_t ws_size,
                              hipStream_t stream) {
  const float* x = (const float*)d_in[0];
  const float* Wq = (const float*)d_in[1];
  const float* Wk = (const float*)d_in[2];
  const float* Wv = (const float*)d_in[3];
  const float* Wp = (const float*)d_in[4];
  float* out = (float*)d_out;

  const size_t MB = 1024 * 1024;
  char* ws = (char*)d_ws;
  bf16* xb = (bf16*)(ws);             // 16 MB; reused as yb after QKV
  bf16* qb = (bf16*)(ws + 16 * MB);   // 16 MB
  bf16* kb = (bf16*)(ws + 32 * MB);   // 16 MB
  bf16* vtb = (bf16*)(ws + 48 * MB);  // 16 MB, V transposed [bh][d][tau(t)]
  bf16* wqb = (bf16*)(ws + 64 * MB);  // 2 MB each
  bf16* wkb = (bf16*)(ws + 66 * MB);
  bf16* wvb = (bf16*)(ws + 68 * MB);
  bf16* wpb = (bf16*)(ws + 70 * MB);
  bf16* yb = xb;

  cvt_all<<<12288, 256, 0, stream>>>(x, Wq, Wk, Wv, Wp, xb, wqb, wkb, wvb, wpb);
  gemm_qkv<<<dim3(8, 32, 3), 512, 0, stream>>>(xb, wqb, wkb, wvb, qb, kb, vtb);
  attn<<<dim3(64, 16), 256, 0, stream>>>(qb, kb, vtb, yb);
  gemm_proj<<<dim3(8, 32), 512, 0, stream>>>(yb, wpb, out);
}

// Round 4
// 258.692 us; speedup vs baseline: 1.1587x; 1.0737x over previous
//
#include <hip/hip_runtime.h>
#include <hip/hip_bf16.h>
#include <math.h>

typedef __hip_bfloat16 bf16;
typedef __attribute__((ext_vector_type(8))) short short8;
typedef __attribute__((ext_vector_type(4))) float f32x4;
typedef __attribute__((ext_vector_type(2))) unsigned uint2v;
typedef __attribute__((ext_vector_type(4))) unsigned uint4v;

#define MFMA_BF16(a, b, c) __builtin_amdgcn_mfma_f32_16x16x32_bf16((a), (b), (c), 0, 0, 0)

// async global->LDS, 16B per lane (m97 pattern). LDS dest must be base + lane*16.
__device__ __forceinline__ void async_copy16(const bf16* g, bf16* l) {
  __builtin_amdgcn_global_load_lds(
      (const __attribute__((address_space(1))) void*)g,
      (__attribute__((address_space(3))) void*)l,
      16, 0, 0);
}

__device__ __forceinline__ unsigned short f2bf_bits(float f) {
  bf16 h = __float2bfloat16(f);
  return *reinterpret_cast<unsigned short*>(&h);
}

// pack 2 f32 -> 2 bf16 in one u32 (lo = first arg). No builtin on gfx950 (m240).
__device__ __forceinline__ unsigned cvt_pk_bf16(float lo, float hi) {
  unsigned r;
  asm("v_cvt_pk_bf16_f32 %0, %1, %2" : "=v"(r) : "v"(lo), "v"(hi));
  return r;
}

// ------------------------------------------- all fp32 -> bf16 in one launch
__global__ __launch_bounds__(256) void cvt_all(const float* __restrict__ x,
                                               const float* __restrict__ wq,
                                               const float* __restrict__ wk,
                                               const float* __restrict__ wv,
                                               const float* __restrict__ wp,
                                               bf16* __restrict__ xb, bf16* __restrict__ wqb,
                                               bf16* __restrict__ wkb, bf16* __restrict__ wvb,
                                               bf16* __restrict__ wpb) {
  const int bid = blockIdx.x;
  const float* in;
  bf16* out;
  int off;
  float scale = 1.0f;
  if (bid < 8192) {
    in = x; out = xb; off = bid;
  } else if (bid < 9216) {
    in = wq; out = wqb; off = bid - 8192;
    scale = 0.180336880111112f;  // 0.125 * log2(e) folded into Wq
  } else if (bid < 10240) {
    in = wk; out = wkb; off = bid - 9216;
  } else if (bid < 11264) {
    in = wv; out = wvb; off = bid - 10240;
  } else {
    in = wp; out = wpb; off = bid - 11264;
  }
  const int i = off * 256 + threadIdx.x;
  float4 v = reinterpret_cast<const float4*>(in)[i];
  ushort4 u;
  u.x = f2bf_bits(v.x * scale);
  u.y = f2bf_bits(v.y * scale);
  u.z = f2bf_bits(v.z * scale);
  u.w = f2bf_bits(v.w * scale);
  reinterpret_cast<ushort4*>(out)[i] = u;
}

// ---------------- fused 256x128 GEMM core: C_z = A * W_z^T for z in [0,NZ)
// R4 theory: the GEMMs were staging-traffic-bound (R3's schedule change was
// neutral). This core stages each A-tile ONCE and runs NZ weight tiles
// against it (NZ=3 cuts A-traffic 3x), and the launcher maps blocks so each
// XCD's 32 CUs share {4 by} x {8 bx} -> A panels and B slices are L2-reused.
//  * BK=32, 3-buffer LDS ring (NZ=3: 120KB): step T reads buf T%3, stages
//    tile T+2 into buf (T+2)%3 (read-complete since step T-1's lgkmcnt(0)
//    precedes its trailing barrier). 5 loads/thread/step (NZ=3).
//  * counted vmcnt: outstanding after stage = 2 tiles -> vmcnt(5) [NZ=3] /
//    vmcnt(3) [NZ=1] confirms tile T+1; tail drains to 0. Never drain-0 in
//    steady state.
//  * LDS XOR swizzle for 64B rows (as R3, verified): chunk ^= (row>>1)&3,
//    linear DMA dest + inverse-swizzled global source + same XOR on read.
//  * raw s_barrier; lgkmcnt(0)+sched_barrier(0) before MFMA (rule 18);
//    setprio(1) around the 16*NZ-MFMA cluster.
template <int NZ>
__device__ __forceinline__ void gemm_fused_core(const bf16* __restrict__ A,
                                                const bf16* __restrict__ w0,
                                                const bf16* __restrict__ w1,
                                                const bf16* __restrict__ w2,
                                                int bx, int by,
                                                f32x4 (&acc)[NZ][4][4]) {
  __shared__ __align__(16) bf16 L[3][8192 + NZ * 4096];
  const int t = threadIdx.x;
  const int lane = t & 63;
  const int l15 = lane & 15;
  const int quad = (lane >> 4) & 3;
  const int wave = t >> 6;
  const int wm = (wave >> 1) * 64;  // 4 M-groups of 64 rows
  const int wn = (wave & 1) * 64;   // 2 N-groups of 64 cols
  const int K = 1024;

  const f32x4 zero = {0.f, 0.f, 0.f, 0.f};
#pragma unroll
  for (int z = 0; z < NZ; ++z)
#pragma unroll
    for (int m = 0; m < 4; ++m)
#pragma unroll
      for (int n = 0; n < 4; ++n) acc[z][m][n] = zero;

  // staging: thread t owns LDS slot (row=t>>2, chunk=t&3); swizzled source
  // chunk = (t&3) ^ ((t>>3)&3) (f(row)=(row>>1)&3; row=t>>2). Rows +128 keep
  // the same f bits.
  const int srow = t >> 2;
  const int schunk = ((t & 3) ^ ((t >> 3) & 3)) * 8;
  const bf16* ga0 = A + (size_t)(by * 256 + srow) * K + schunk;
  const bf16* ga1 = ga0 + (size_t)128 * K;
  const bf16* ws[3] = {w0, w1, w2};
  const bf16* gw[NZ];
#pragma unroll
  for (int z = 0; z < NZ; ++z)
    gw[z] = ws[z] + (size_t)(bx * 128 + srow) * K + schunk;

  // fragment reads: row = w? + {m,n}*16 + l15 -> f(row) = (l15>>1)&3
  const int fsw = (quad ^ ((l15 >> 1) & 3)) * 8;
  const int arow = (wm + l15) * 32 + fsw;  // + m*512
  const int brow = (wn + l15) * 32 + fsw;  // + 8192 + z*4096 + n*512

  auto stage = [&](int kt) {
    bf16* Ld = &L[kt % 3][0];
    async_copy16(ga0 + kt * 32, Ld + t * 8);
    async_copy16(ga1 + kt * 32, Ld + 4096 + t * 8);
#pragma unroll
    for (int z = 0; z < NZ; ++z)
      async_copy16(gw[z] + kt * 32, Ld + 8192 + z * 4096 + t * 8);
  };

  // prologue: stage tiles 0,1; wait for tile 0 (oldest NZ+2 loads)
  stage(0);
  stage(1);
  if constexpr (NZ == 3)
    asm volatile("s_waitcnt vmcnt(5)" ::: "memory");
  else
    asm volatile("s_waitcnt vmcnt(3)" ::: "memory");
  __builtin_amdgcn_s_barrier();

  for (int T = 0; T < 32; ++T) {
    const bf16* Lb = &L[T % 3][0];
    short8 af[4];
#pragma unroll
    for (int m = 0; m < 4; ++m)
      af[m] = *reinterpret_cast<const short8*>(Lb + arow + m * 512);
    if (T <= 29) {
      stage(T + 2);
      if constexpr (NZ == 3)
        asm volatile("s_waitcnt vmcnt(5)" ::: "memory");
      else
        asm volatile("s_waitcnt vmcnt(3)" ::: "memory");
    } else {
      asm volatile("s_waitcnt vmcnt(0)" ::: "memory");
    }
    __builtin_amdgcn_s_barrier();
    asm volatile("s_waitcnt lgkmcnt(0)" ::: "memory");
    __builtin_amdgcn_sched_barrier(0);
    __builtin_amdgcn_s_setprio(1);
#pragma unroll
    for (int z = 0; z < NZ; ++z) {
      short8 bfr[4];
#pragma unroll
      for (int n = 0; n < 4; ++n)
        bfr[n] = *reinterpret_cast<const short8*>(Lb + 8192 + z * 4096 + brow + n * 512);
#pragma unroll
      for (int m = 0; m < 4; ++m)
#pragma unroll
        for (int n = 0; n < 4; ++n) acc[z][m][n] = MFMA_BF16(af[m], bfr[n], acc[z][m][n]);
    }
    __builtin_amdgcn_s_setprio(0);
    __builtin_amdgcn_sched_barrier(0);
    __builtin_amdgcn_s_barrier();
  }
}

// block id -> (bx, by) so XCD x (= id%8 round-robin) owns by in [4x, 4x+4) and
// all 8 bx: its 32 concurrent blocks L2-share 4 A-panels (512KB each) and the
// B slices. 256 blocks = 1 block/CU = exactly 1 round.
__device__ __forceinline__ void xcd_map(int i, int& bx, int& by) {
  bx = (i >> 3) & 7;
  by = (i & 7) * 4 + (i >> 6);
}

// fused q/k/v projection: grid 256 blocks x 512 threads. z==2 (V) writes
// TRANSPOSED into vt[(b*1024 + col)*2048 + tau(t)] ([bh][d][t], t bits 2,3
// swapped inside each 32-key block -- matches attn's permlane k-permutation).
__global__ __launch_bounds__(512, 2) void gemm_qkv(const bf16* __restrict__ x,
                                                   const bf16* __restrict__ wq,
                                                   const bf16* __restrict__ wk,
                                                   const bf16* __restrict__ wv,
                                                   bf16* __restrict__ q, bf16* __restrict__ k,
                                                   bf16* __restrict__ vt) {
  int bx, by;
  xcd_map(blockIdx.x, bx, by);
  f32x4 acc[3][4][4];
  gemm_fused_core<3>(x, wq, wk, wv, bx, by, acc);
  const int t = threadIdx.x, lane = t & 63, l15 = lane & 15, quad = (lane >> 4) & 3,
            wave = t >> 6;
  const int wm = (wave >> 1) * 64, wn = (wave & 1) * 64;
  const int rb = by * 256 + wm + quad * 4;
  const int cbb = bx * 128 + wn + l15;
#pragma unroll
  for (int z = 0; z < 2; ++z) {
    bf16* C = z ? k : q;
#pragma unroll
    for (int m = 0; m < 4; ++m)
#pragma unroll
      for (int n = 0; n < 4; ++n)
#pragma unroll
        for (int r = 0; r < 4; ++r)
          C[(size_t)(rb + m * 16 + r) * 1024 + cbb + n * 16] = __float2bfloat16(acc[z][m][n][r]);
  }
#pragma unroll
  for (int m = 0; m < 4; ++m)
#pragma unroll
    for (int n = 0; n < 4; ++n) {
      const int tg = rb + m * 16;
      const int col = cbb + n * 16;
      const int b = tg >> 11, tl = tg & 2047;
      const int tls = (tl & ~12) | ((tl & 4) << 1) | ((tl & 8) >> 1);  // tau
      ushort4 pk;
      pk.x = f2bf_bits(acc[2][m][n][0]);
      pk.y = f2bf_bits(acc[2][m][n][1]);
      pk.z = f2bf_bits(acc[2][m][n][2]);
      pk.w = f2bf_bits(acc[2][m][n][3]);
      *reinterpret_cast<ushort4*>(&vt[((size_t)(b * 1024 + col)) * 2048 + tls]) = pk;
    }
}

// output projection: same core at NZ=1, grid 256 blocks, fp32 out
__global__ __launch_bounds__(512, 2) void gemm_proj(const bf16* __restrict__ y,
                                                    const bf16* __restrict__ wp,
                                                    float* __restrict__ outp) {
  int bx, by;
  xcd_map(blockIdx.x, bx, by);
  f32x4 acc[1][4][4];
  gemm_fused_core<1>(y, wp, wp, wp, bx, by, acc);
  const int t = threadIdx.x, lane = t & 63, l15 = lane & 15, quad = (lane >> 4) & 3,
            wave = t >> 6;
  const int wm = (wave >> 1) * 64, wn = (wave & 1) * 64;
  const int rb = by * 256 + wm + quad * 4;
  const int cbb = bx * 128 + wn + l15;
#pragma unroll
  for (int m = 0; m < 4; ++m)
#pragma unroll
    for (int n = 0; n < 4; ++n)
#pragma unroll
      for (int r = 0; r < 4; ++r)
        outp[(size_t)(rb + m * 16 + r) * 1024 + cbb + n * 16] = acc[0][m][n][r];
}

// ----------------------------------------------------------- flash attention
// (unchanged from R2/R3 -- isolate the GEMM change this round)
__global__ __launch_bounds__(256) void attn(const bf16* __restrict__ qb,
                                            const bf16* __restrict__ kb,
                                            const bf16* __restrict__ vt,
                                            bf16* __restrict__ yb) {
  __shared__ __align__(16) bf16 Ks[2][2048];
  __shared__ __align__(16) bf16 Vs[2][2048];
  const int tid = threadIdx.x;
  const int lane = tid & 63, l15 = lane & 15, quad = lane >> 4, wave = tid >> 6;
  const int p = blockIdx.y;
  const int bh = blockIdx.x;
  const int b = bh >> 4, h = bh & 15;
  const size_t rowbase = (size_t)b * 2048;
  const int cb = h * 64;

  const int tlo = p, thi = 31 - p;
  const int gq0[2] = {tlo * 64 + wave * 16, thi * 64 + wave * 16};

  short8 aq[2][2];
#pragma unroll
  for (int g = 0; g < 2; ++g) {
    const bf16* qp = qb + (rowbase + gq0[g] + l15) * 1024 + cb + quad * 8;
    aq[g][0] = *reinterpret_cast<const short8*>(qp);
    aq[g][1] = *reinterpret_cast<const short8*>(qp + 32);
  }

  short8 ones;
#pragma unroll
  for (int i = 0; i < 8; ++i) ones[i] = (short)0x3F80;  // bf16 1.0

  f32x4 o[2][4], l4[2];
  const f32x4 zero = {0.f, 0.f, 0.f, 0.f};
#pragma unroll
  for (int g = 0; g < 2; ++g) {
#pragma unroll
    for (int dt = 0; dt < 4; ++dt) o[g][dt] = zero;
    l4[g] = zero;
  }

  const int sdq = (((tid & 3) ^ ((tid >> 2) & 3) ^ ((tid >> 4) & 3))) * 8;
  const bf16* kg = kb + (rowbase + ((tid & 127) >> 2)) * 1024 + cb + (tid >> 7) * 32 + sdq;
  const bf16* vg = vt + ((size_t)bh * 64 + (tid >> 2)) * 2048 + sdq;
  const int csw = (quad ^ (l15 & 3) ^ ((l15 >> 2) & 3)) * 8;

  const int nkt = 2 * thi + 2;
  async_copy16(kg, &Ks[0][tid * 8]);
  async_copy16(vg, &Vs[0][tid * 8]);

  for (int kt = 0; kt < nkt; ++kt) {
    const int buf = kt & 1;
    __syncthreads();  // tile kt resident; prior reads of buf^1 done
    if (kt + 1 < nkt) {
      async_copy16(kg + (size_t)(kt + 1) * 32 * 1024, &Ks[buf ^ 1][tid * 8]);
      async_copy16(vg + (kt + 1) * 32, &Vs[buf ^ 1][tid * 8]);
    }
    const int k0g = kt * 32;
    if (k0g > gq0[1] + 15) continue;

    short8 bk[2][2];
#pragma unroll
    for (int j = 0; j < 2; ++j)
#pragma unroll
      for (int ks = 0; ks < 2; ++ks)
        bk[j][ks] = *reinterpret_cast<const short8*>(
            &Ks[buf][ks * 1024 + (j * 16 + l15) * 32 + csw]);
    short8 av[4];
#pragma unroll
    for (int dt = 0; dt < 4; ++dt)
      av[dt] = *reinterpret_cast<const short8*>(&Vs[buf][(dt * 16 + l15) * 32 + csw]);

#pragma unroll
    for (int g = 0; g < 2; ++g) {
      if (k0g > gq0[g] + 15) continue;
      f32x4 st[2];
#pragma unroll
      for (int j = 0; j < 2; ++j) {
        st[j] = MFMA_BF16(bk[j][0], aq[g][0], zero);
        st[j] = MFMA_BF16(bk[j][1], aq[g][1], st[j]);
      }
      const bool need_mask = (k0g + 31 > gq0[g]);
      unsigned w[2][2];
#pragma unroll
      for (int j = 0; j < 2; ++j) {
        float pw[4];
#pragma unroll
        for (int r = 0; r < 4; ++r) {
          float val = st[j][r];
          if (need_mask && (k0g + j * 16 + quad * 4 + r) > (gq0[g] + l15))
            val = -INFINITY;
          pw[r] = __builtin_amdgcn_exp2f(val);
        }
        w[j][0] = cvt_pk_bf16(pw[0], pw[1]);
        w[j][1] = cvt_pk_bf16(pw[2], pw[3]);
      }
      uint2v s0 = __builtin_amdgcn_permlane32_swap(w[0][0], w[1][0], false, false);
      uint2v s1 = __builtin_amdgcn_permlane32_swap(w[0][1], w[1][1], false, false);
      uint4v u;
      u[0] = s0[0];
      u[1] = s1[0];
      u[2] = s0[1];
      u[3] = s1[1];
      const short8 bp = __builtin_bit_cast(short8, u);
#pragma unroll
      for (int dt = 0; dt < 4; ++dt) o[g][dt] = MFMA_BF16(av[dt], bp, o[g][dt]);
      l4[g] = MFMA_BF16(ones, bp, l4[g]);
    }
  }

#pragma unroll
  for (int g = 0; g < 2; ++g) {
    const float invl = 1.f / l4[g][0];
    bf16* yp = yb + (rowbase + gq0[g] + l15) * 1024 + cb + quad * 4;
#pragma unroll
    for (int dt = 0; dt < 4; ++dt) {
      ushort4 pk;
      pk.x = f2bf_bits(o[g][dt][0] * invl);
      pk.y = f2bf_bits(o[g][dt][1] * invl);
      pk.z = f2bf_bits(o[g][dt][2] * invl);
      pk.w = f2bf_bits(o[g][dt][3] * invl);
      *reinterpret_cast<ushort4*>(&yp[dt * 16]) = pk;
    }
  }
}

// ---------------------------------------------------------------------- launch
extern "C" void kernel_launch(void* const* d_in, const int* in_sizes, int n_in,
                              void* d_out, int out_size, void* d_ws, size_t ws_size,
                              hipStream_t stream) {
  const float* x = (const float*)d_in[0];
  const float* Wq = (const float*)d_in[1];
  const float* Wk = (const float*)d_in[2];
  const float* Wv = (const float*)d_in[3];
  const float* Wp = (const float*)d_in[4];
  float* out = (float*)d_out;

  const size_t MB = 1024 * 1024;
  char* ws = (char*)d_ws;
  bf16* xb = (bf16*)(ws);             // 16 MB; reused as yb after QKV
  bf16* qb = (bf16*)(ws + 16 * MB);   // 16 MB
  bf16* kb = (bf16*)(ws + 32 * MB);   // 16 MB
  bf16* vtb = (bf16*)(ws + 48 * MB);  // 16 MB, V transposed [bh][d][tau(t)]
  bf16* wqb = (bf16*)(ws + 64 * MB);  // 2 MB each
  bf16* wkb = (bf16*)(ws + 66 * MB);
  bf16* wvb = (bf16*)(ws + 68 * MB);
  bf16* wpb = (bf16*)(ws + 70 * MB);
  bf16* yb = xb;

  cvt_all<<<12288, 256, 0, stream>>>(x, Wq, Wk, Wv, Wp, xb, wqb, wkb, wvb, wpb);
  gemm_qkv<<<256, 512, 0, stream>>>(xb, wqb, wkb, wvb, qb, kb, vtb);
  attn<<<dim3(64, 16), 256, 0, stream>>>(qb, kb, vtb, yb);
  gemm_proj<<<256, 512, 0, stream>>>(yb, wpb, out);
}

// Round 5
// 244.624 us; speedup vs baseline: 1.2253x; 1.0575x over previous
//
#include <hip/hip_runtime.h>
#include <hip/hip_bf16.h>
#include <math.h>

typedef __hip_bfloat16 bf16;
typedef __attribute__((ext_vector_type(8))) short short8;
typedef __attribute__((ext_vector_type(4))) float f32x4;
typedef __attribute__((ext_vector_type(2))) unsigned uint2v;
typedef __attribute__((ext_vector_type(4))) unsigned uint4v;

#define MFMA_BF16(a, b, c) __builtin_amdgcn_mfma_f32_16x16x32_bf16((a), (b), (c), 0, 0, 0)

// async global->LDS, 16B per lane (m97 pattern). LDS dest must be base + lane*16.
__device__ __forceinline__ void async_copy16(const bf16* g, bf16* l) {
  __builtin_amdgcn_global_load_lds(
      (const __attribute__((address_space(1))) void*)g,
      (__attribute__((address_space(3))) void*)l,
      16, 0, 0);
}

__device__ __forceinline__ unsigned short f2bf_bits(float f) {
  bf16 h = __float2bfloat16(f);
  return *reinterpret_cast<unsigned short*>(&h);
}

// pack 2 f32 -> 2 bf16 in one u32 (lo = first arg). No builtin on gfx950 (m240).
__device__ __forceinline__ unsigned cvt_pk_bf16(float lo, float hi) {
  unsigned r;
  asm("v_cvt_pk_bf16_f32 %0, %1, %2" : "=v"(r) : "v"(lo), "v"(hi));
  return r;
}

// ------------------------------------------- all fp32 -> bf16 in one launch
__global__ __launch_bounds__(256) void cvt_all(const float* __restrict__ x,
                                               const float* __restrict__ wq,
                                               const float* __restrict__ wk,
                                               const float* __restrict__ wv,
                                               const float* __restrict__ wp,
                                               bf16* __restrict__ xb, bf16* __restrict__ wqb,
                                               bf16* __restrict__ wkb, bf16* __restrict__ wvb,
                                               bf16* __restrict__ wpb) {
  const int bid = blockIdx.x;
  const float* in;
  bf16* out;
  int off;
  float scale = 1.0f;
  if (bid < 8192) {
    in = x; out = xb; off = bid;
  } else if (bid < 9216) {
    in = wq; out = wqb; off = bid - 8192;
    scale = 0.180336880111112f;  // 0.125 * log2(e) folded into Wq
  } else if (bid < 10240) {
    in = wk; out = wkb; off = bid - 9216;
  } else if (bid < 11264) {
    in = wv; out = wvb; off = bid - 10240;
  } else {
    in = wp; out = wpb; off = bid - 11264;
  }
  const int i = off * 256 + threadIdx.x;
  float4 v = reinterpret_cast<const float4*>(in)[i];
  ushort4 u;
  u.x = f2bf_bits(v.x * scale);
  u.y = f2bf_bits(v.y * scale);
  u.z = f2bf_bits(v.z * scale);
  u.w = f2bf_bits(v.w * scale);
  reinterpret_cast<ushort4*>(out)[i] = u;
}

// ---------------- fused 256x128 GEMM core: C_z = A * W_z^T for z in [0,NZ)
// (unchanged from R4 -- best known GEMM config; attn is this round's target)
template <int NZ>
__device__ __forceinline__ void gemm_fused_core(const bf16* __restrict__ A,
                                                const bf16* __restrict__ w0,
                                                const bf16* __restrict__ w1,
                                                const bf16* __restrict__ w2,
                                                int bx, int by,
                                                f32x4 (&acc)[NZ][4][4]) {
  __shared__ __align__(16) bf16 L[3][8192 + NZ * 4096];
  const int t = threadIdx.x;
  const int lane = t & 63;
  const int l15 = lane & 15;
  const int quad = (lane >> 4) & 3;
  const int wave = t >> 6;
  const int wm = (wave >> 1) * 64;  // 4 M-groups of 64 rows
  const int wn = (wave & 1) * 64;   // 2 N-groups of 64 cols
  const int K = 1024;

  const f32x4 zero = {0.f, 0.f, 0.f, 0.f};
#pragma unroll
  for (int z = 0; z < NZ; ++z)
#pragma unroll
    for (int m = 0; m < 4; ++m)
#pragma unroll
      for (int n = 0; n < 4; ++n) acc[z][m][n] = zero;

  const int srow = t >> 2;
  const int schunk = ((t & 3) ^ ((t >> 3) & 3)) * 8;
  const bf16* ga0 = A + (size_t)(by * 256 + srow) * K + schunk;
  const bf16* ga1 = ga0 + (size_t)128 * K;
  const bf16* ws[3] = {w0, w1, w2};
  const bf16* gw[NZ];
#pragma unroll
  for (int z = 0; z < NZ; ++z)
    gw[z] = ws[z] + (size_t)(bx * 128 + srow) * K + schunk;

  const int fsw = (quad ^ ((l15 >> 1) & 3)) * 8;
  const int arow = (wm + l15) * 32 + fsw;  // + m*512
  const int brow = (wn + l15) * 32 + fsw;  // + 8192 + z*4096 + n*512

  auto stage = [&](int kt) {
    bf16* Ld = &L[kt % 3][0];
    async_copy16(ga0 + kt * 32, Ld + t * 8);
    async_copy16(ga1 + kt * 32, Ld + 4096 + t * 8);
#pragma unroll
    for (int z = 0; z < NZ; ++z)
      async_copy16(gw[z] + kt * 32, Ld + 8192 + z * 4096 + t * 8);
  };

  stage(0);
  stage(1);
  if constexpr (NZ == 3)
    asm volatile("s_waitcnt vmcnt(5)" ::: "memory");
  else
    asm volatile("s_waitcnt vmcnt(3)" ::: "memory");
  __builtin_amdgcn_s_barrier();

  for (int T = 0; T < 32; ++T) {
    const bf16* Lb = &L[T % 3][0];
    short8 af[4];
#pragma unroll
    for (int m = 0; m < 4; ++m)
      af[m] = *reinterpret_cast<const short8*>(Lb + arow + m * 512);
    if (T <= 29) {
      stage(T + 2);
      if constexpr (NZ == 3)
        asm volatile("s_waitcnt vmcnt(5)" ::: "memory");
      else
        asm volatile("s_waitcnt vmcnt(3)" ::: "memory");
    } else {
      asm volatile("s_waitcnt vmcnt(0)" ::: "memory");
    }
    __builtin_amdgcn_s_barrier();
    asm volatile("s_waitcnt lgkmcnt(0)" ::: "memory");
    __builtin_amdgcn_sched_barrier(0);
    __builtin_amdgcn_s_setprio(1);
#pragma unroll
    for (int z = 0; z < NZ; ++z) {
      short8 bfr[4];
#pragma unroll
      for (int n = 0; n < 4; ++n)
        bfr[n] = *reinterpret_cast<const short8*>(Lb + 8192 + z * 4096 + brow + n * 512);
#pragma unroll
      for (int m = 0; m < 4; ++m)
#pragma unroll
        for (int n = 0; n < 4; ++n) acc[z][m][n] = MFMA_BF16(af[m], bfr[n], acc[z][m][n]);
    }
    __builtin_amdgcn_s_setprio(0);
    __builtin_amdgcn_sched_barrier(0);
    __builtin_amdgcn_s_barrier();
  }
}

// block id -> (bx, by): XCD x owns by in [4x,4x+4) x all 8 bx (L2 reuse).
__device__ __forceinline__ void xcd_map(int i, int& bx, int& by) {
  bx = (i >> 3) & 7;
  by = (i & 7) * 4 + (i >> 6);
}

// fused q/k/v projection: grid 256 blocks x 512 threads. z==2 (V) writes
// TRANSPOSED into vt[(b*1024 + col)*2048 + tau(t)].
__global__ __launch_bounds__(512, 2) void gemm_qkv(const bf16* __restrict__ x,
                                                   const bf16* __restrict__ wq,
                                                   const bf16* __restrict__ wk,
                                                   const bf16* __restrict__ wv,
                                                   bf16* __restrict__ q, bf16* __restrict__ k,
                                                   bf16* __restrict__ vt) {
  int bx, by;
  xcd_map(blockIdx.x, bx, by);
  f32x4 acc[3][4][4];
  gemm_fused_core<3>(x, wq, wk, wv, bx, by, acc);
  const int t = threadIdx.x, lane = t & 63, l15 = lane & 15, quad = (lane >> 4) & 3,
            wave = t >> 6;
  const int wm = (wave >> 1) * 64, wn = (wave & 1) * 64;
  const int rb = by * 256 + wm + quad * 4;
  const int cbb = bx * 128 + wn + l15;
#pragma unroll
  for (int z = 0; z < 2; ++z) {
    bf16* C = z ? k : q;
#pragma unroll
    for (int m = 0; m < 4; ++m)
#pragma unroll
      for (int n = 0; n < 4; ++n)
#pragma unroll
        for (int r = 0; r < 4; ++r)
          C[(size_t)(rb + m * 16 + r) * 1024 + cbb + n * 16] = __float2bfloat16(acc[z][m][n][r]);
  }
#pragma unroll
  for (int m = 0; m < 4; ++m)
#pragma unroll
    for (int n = 0; n < 4; ++n) {
      const int tg = rb + m * 16;
      const int col = cbb + n * 16;
      const int b = tg >> 11, tl = tg & 2047;
      const int tls = (tl & ~12) | ((tl & 4) << 1) | ((tl & 8) >> 1);  // tau
      ushort4 pk;
      pk.x = f2bf_bits(acc[2][m][n][0]);
      pk.y = f2bf_bits(acc[2][m][n][1]);
      pk.z = f2bf_bits(acc[2][m][n][2]);
      pk.w = f2bf_bits(acc[2][m][n][3]);
      *reinterpret_cast<ushort4*>(&vt[((size_t)(b * 1024 + col)) * 2048 + tls]) = pk;
    }
}

// output projection: same core at NZ=1, grid 256 blocks, fp32 out
__global__ __launch_bounds__(512, 2) void gemm_proj(const bf16* __restrict__ y,
                                                    const bf16* __restrict__ wp,
                                                    float* __restrict__ outp) {
  int bx, by;
  xcd_map(blockIdx.x, bx, by);
  f32x4 acc[1][4][4];
  gemm_fused_core<1>(y, wp, wp, wp, bx, by, acc);
  const int t = threadIdx.x, lane = t & 63, l15 = lane & 15, quad = (lane >> 4) & 3,
            wave = t >> 6;
  const int wm = (wave >> 1) * 64, wn = (wave & 1) * 64;
  const int rb = by * 256 + wm + quad * 4;
  const int cbb = bx * 128 + wn + l15;
#pragma unroll
  for (int m = 0; m < 4; ++m)
#pragma unroll
    for (int n = 0; n < 4; ++n)
#pragma unroll
      for (int r = 0; r < 4; ++r)
        outp[(size_t)(rb + m * 16 + r) * 1024 + cbb + n * 16] = acc[0][m][n][r];
}

// ----------------------------------------------------------- flash attention
// v5: KVBLK=64 (was 32). Halves iteration count, barriers, staging issue
// points and loop overhead; per-key exp2/MFMA/ds_read unchanged.
//  * LDS tiles [64 rows][64 elems] (128B rows, 8x16B chunks): G4 swizzle
//    chunk ^= row&7 (3-bit), rule-21 both-sides (linear DMA dest,
//    inverse-swizzled global source, same XOR on fragment read).
//  * P path identical to R2-verified mapping, applied per 32-key half:
//    pairs (j0,j1)=(0,1) and (2,3) -> bp[0], bp[1]; pi/tau unchanged
//    (32-block-local).
//  * jlim: on diagonal tiles, skip fully-masked 16-key j-blocks
//    (wave-uniform); their w[] packed P-words are zero.
__global__ __launch_bounds__(256, 3) void attn(const bf16* __restrict__ qb,
                                               const bf16* __restrict__ kb,
                                               const bf16* __restrict__ vt,
                                               bf16* __restrict__ yb) {
  __shared__ __align__(16) bf16 Ks[2][4096];
  __shared__ __align__(16) bf16 Vs[2][4096];
  const int tid = threadIdx.x;
  const int lane = tid & 63, l15 = lane & 15, quad = lane >> 4, wave = tid >> 6;
  const int p = blockIdx.y;
  const int bh = blockIdx.x;
  const int b = bh >> 4, h = bh & 15;
  const size_t rowbase = (size_t)b * 2048;
  const int cb = h * 64;

  const int tlo = p, thi = 31 - p;
  const int gq0[2] = {tlo * 64 + wave * 16, thi * 64 + wave * 16};

  short8 aq[2][2];
#pragma unroll
  for (int g = 0; g < 2; ++g) {
    const bf16* qp = qb + (rowbase + gq0[g] + l15) * 1024 + cb + quad * 8;
    aq[g][0] = *reinterpret_cast<const short8*>(qp);
    aq[g][1] = *reinterpret_cast<const short8*>(qp + 32);
  }

  short8 ones;
#pragma unroll
  for (int i = 0; i < 8; ++i) ones[i] = (short)0x3F80;  // bf16 1.0

  f32x4 o[2][4], l4[2];
  const f32x4 zero = {0.f, 0.f, 0.f, 0.f};
#pragma unroll
  for (int g = 0; g < 2; ++g) {
#pragma unroll
    for (int dt = 0; dt < 4; ++dt) o[g][dt] = zero;
    l4[g] = zero;
  }

  // staging: thread tid owns LDS slots (row = i*32 + tid>>3, chunk = tid&7)
  // for DMA i in {0,1}; fetches global chunk (tid&7) ^ ((tid>>3)&7)
  // (f(row) = row&7; rows +32 keep the same low bits).
  const int srow = tid >> 3;                    // 0..31
  const int sc = (tid & 7) ^ (srow & 7);        // swizzled source chunk
  const bf16* kg = kb + (rowbase + srow) * 1024 + cb + sc * 8;
  const bf16* vg = vt + ((size_t)bh * 64 + srow) * 2048 + sc * 8;
  const int fx = l15 & 7;  // fragment-read XOR: row&7 = l15&7 for all frags

  const int nkt = thi + 1;
  // prologue: stage tile 0 (K rows 0-31, 32-63; V d-rows 0-31, 32-63)
  async_copy16(kg, &Ks[0][tid * 8]);
  async_copy16(kg + 32 * 1024, &Ks[0][2048 + tid * 8]);
  async_copy16(vg, &Vs[0][tid * 8]);
  async_copy16(vg + (size_t)32 * 2048, &Vs[0][2048 + tid * 8]);

  for (int kt = 0; kt < nkt; ++kt) {
    const int buf = kt & 1;
    __syncthreads();  // tile kt resident; prior reads of buf^1 done
    if (kt + 1 < nkt) {
      const bf16* kgn = kg + (size_t)(kt + 1) * 64 * 1024;
      const bf16* vgn = vg + (kt + 1) * 64;
      async_copy16(kgn, &Ks[buf ^ 1][tid * 8]);
      async_copy16(kgn + 32 * 1024, &Ks[buf ^ 1][2048 + tid * 8]);
      async_copy16(vgn, &Vs[buf ^ 1][tid * 8]);
      async_copy16(vgn + (size_t)32 * 2048, &Vs[buf ^ 1][2048 + tid * 8]);
    }
    const int k0g = kt * 64;

    // K fragments, shared by both q-groups: row = j*16+l15 (key), 8 d per reg
    short8 bk[4][2];
#pragma unroll
    for (int j = 0; j < 4; ++j)
#pragma unroll
      for (int ks = 0; ks < 2; ++ks)
        bk[j][ks] = *reinterpret_cast<const short8*>(
            &Ks[buf][(j * 16 + l15) * 64 + (((ks * 4 + quad) ^ fx)) * 8]);

#pragma unroll
    for (int g = 0; g < 2; ++g) {
      if (k0g > gq0[g] + 15) continue;
      // swapped QK^T: st[j] = K*Q^T (S^T). col = q = l15, row = k.
      f32x4 st[4];
#pragma unroll
      for (int j = 0; j < 4; ++j) {
        st[j] = MFMA_BF16(bk[j][0], aq[g][0], zero);
        st[j] = MFMA_BF16(bk[j][1], aq[g][1], st[j]);
      }
      const int rem = gq0[g] + 15 - k0g;  // >=0 when active (wave-uniform)
      const bool need_mask = (k0g + 63 > gq0[g]);
      unsigned w[4][2] = {{0u, 0u}, {0u, 0u}, {0u, 0u}, {0u, 0u}};
#pragma unroll
      for (int j = 0; j < 4; ++j) {
        if (j * 16 <= rem) {  // wave-uniform: skip fully-masked j-blocks
          float pw[4];
#pragma unroll
          for (int r = 0; r < 4; ++r) {
            float val = st[j][r];  // pre-scaled (folded into Wq)
            if (need_mask && (k0g + j * 16 + quad * 4 + r) > (gq0[g] + l15))
              val = -INFINITY;
            pw[r] = __builtin_amdgcn_exp2f(val);
          }
          w[j][0] = cvt_pk_bf16(pw[0], pw[1]);
          w[j][1] = cvt_pk_bf16(pw[2], pw[3]);
        }
      }
      // per 32-key half: permlane32_swap pair (2h, 2h+1) -> B-fragment bp;
      // slot k = half*32 + pi(quad*8+e), matching vt's tau order.
#pragma unroll
      for (int half = 0; half < 2; ++half) {
        uint2v s0 =
            __builtin_amdgcn_permlane32_swap(w[2 * half][0], w[2 * half + 1][0], false, false);
        uint2v s1 =
            __builtin_amdgcn_permlane32_swap(w[2 * half][1], w[2 * half + 1][1], false, false);
        uint4v u;
        u[0] = s0[0];
        u[1] = s1[0];
        u[2] = s0[1];
        u[3] = s1[1];
        const short8 bp = __builtin_bit_cast(short8, u);
#pragma unroll
        for (int dt = 0; dt < 4; ++dt) {
          const short8 av = *reinterpret_cast<const short8*>(
              &Vs[buf][(dt * 16 + l15) * 64 + (((half * 4 + quad) ^ fx)) * 8]);
          o[g][dt] = MFMA_BF16(av, bp, o[g][dt]);
        }
        l4[g] = MFMA_BF16(ones, bp, l4[g]);  // row sums of P (pi-invariant)
      }
    }
  }

  // epilogue: lane holds q = gq0[g]+l15, d = dt*16 + quad*4 + r (r contiguous)
#pragma unroll
  for (int g = 0; g < 2; ++g) {
    const float invl = 1.f / l4[g][0];
    bf16* yp = yb + (rowbase + gq0[g] + l15) * 1024 + cb + quad * 4;
#pragma unroll
    for (int dt = 0; dt < 4; ++dt) {
      ushort4 pk;
      pk.x = f2bf_bits(o[g][dt][0] * invl);
      pk.y = f2bf_bits(o[g][dt][1] * invl);
      pk.z = f2bf_bits(o[g][dt][2] * invl);
      pk.w = f2bf_bits(o[g][dt][3] * invl);
      *reinterpret_cast<ushort4*>(&yp[dt * 16]) = pk;
    }
  }
}

// ---------------------------------------------------------------------- launch
extern "C" void kernel_launch(void* const* d_in, const int* in_sizes, int n_in,
                              void* d_out, int out_size, void* d_ws, size_t ws_size,
                              hipStream_t stream) {
  const float* x = (const float*)d_in[0];
  const float* Wq = (const float*)d_in[1];
  const float* Wk = (const float*)d_in[2];
  const float* Wv = (const float*)d_in[3];
  const float* Wp = (const float*)d_in[4];
  float* out = (float*)d_out;

  const size_t MB = 1024 * 1024;
  char* ws = (char*)d_ws;
  bf16* xb = (bf16*)(ws);             // 16 MB; reused as yb after QKV
  bf16* qb = (bf16*)(ws + 16 * MB);   // 16 MB
  bf16* kb = (bf16*)(ws + 32 * MB);   // 16 MB
  bf16* vtb = (bf16*)(ws + 48 * MB);  // 16 MB, V transposed [bh][d][tau(t)]
  bf16* wqb = (bf16*)(ws + 64 * MB);  // 2 MB each
  bf16* wkb = (bf16*)(ws + 66 * MB);
  bf16* wvb = (bf16*)(ws + 68 * MB);
  bf16* wpb = (bf16*)(ws + 70 * MB);
  bf16* yb = xb;

  cvt_all<<<12288, 256, 0, stream>>>(x, Wq, Wk, Wv, Wp, xb, wqb, wkb, wvb, wpb);
  gemm_qkv<<<256, 512, 0, stream>>>(xb, wqb, wkb, wvb, qb, kb, vtb);
  attn<<<dim3(64, 16), 256, 0, stream>>>(qb, kb, vtb, yb);
  gemm_proj<<<256, 512, 0, stream>>>(yb, wpb, out);
}

// Round 8
// 241.795 us; speedup vs baseline: 1.2396x; 1.0117x over previous
//
#include <hip/hip_runtime.h>
#include <hip/hip_bf16.h>
#include <math.h>

typedef __hip_bfloat16 bf16;
typedef __attribute__((ext_vector_type(8))) short short8;
typedef __attribute__((ext_vector_type(4))) float f32x4;
typedef __attribute__((ext_vector_type(2))) unsigned uint2v;
typedef __attribute__((ext_vector_type(4))) unsigned uint4v;

#define MFMA_BF16(a, b, c) __builtin_amdgcn_mfma_f32_16x16x32_bf16((a), (b), (c), 0, 0, 0)

// async global->LDS, 16B per lane (m97 pattern). LDS dest must be base + lane*16.
__device__ __forceinline__ void async_copy16(const bf16* g, bf16* l) {
  __builtin_amdgcn_global_load_lds(
      (const __attribute__((address_space(1))) void*)g,
      (__attribute__((address_space(3))) void*)l,
      16, 0, 0);
}

__device__ __forceinline__ unsigned short f2bf_bits(float f) {
  bf16 h = __float2bfloat16(f);
  return *reinterpret_cast<unsigned short*>(&h);
}

// pack 2 f32 -> 2 bf16 in one u32 (lo = first arg). No builtin on gfx950 (m240).
__device__ __forceinline__ unsigned cvt_pk_bf16(float lo, float hi) {
  unsigned r;
  asm("v_cvt_pk_bf16_f32 %0, %1, %2" : "=v"(r) : "v"(lo), "v"(hi));
  return r;
}

// ------------------------------------------- all fp32 -> bf16 in one launch
// v8: 2 float4 per thread (6144 blocks). Regions (in float4 units of 512/blk):
// [0,4096): x ; [4096,4608): Wq (pre-scaled 0.125*log2e) ; [4608,5120): Wk ;
// [5120,5632): Wv ; [5632,6144): Wp.
__global__ __launch_bounds__(256) void cvt_all(const float* __restrict__ x,
                                               const float* __restrict__ wq,
                                               const float* __restrict__ wk,
                                               const float* __restrict__ wv,
                                               const float* __restrict__ wp,
                                               bf16* __restrict__ xb, bf16* __restrict__ wqb,
                                               bf16* __restrict__ wkb, bf16* __restrict__ wvb,
                                               bf16* __restrict__ wpb) {
  const int bid = blockIdx.x;
  const float* in;
  bf16* out;
  int off;
  float scale = 1.0f;
  if (bid < 4096) {
    in = x; out = xb; off = bid;
  } else if (bid < 4608) {
    in = wq; out = wqb; off = bid - 4096;
    scale = 0.180336880111112f;  // 0.125 * log2(e) folded into Wq
  } else if (bid < 5120) {
    in = wk; out = wkb; off = bid - 4608;
  } else if (bid < 5632) {
    in = wv; out = wvb; off = bid - 5120;
  } else {
    in = wp; out = wpb; off = bid - 5632;
  }
  const int base = off * 512 + threadIdx.x * 2;
#pragma unroll
  for (int u = 0; u < 2; ++u) {
    const int i = base + u;
    float4 v = reinterpret_cast<const float4*>(in)[i];
    ushort4 pk;
    pk.x = f2bf_bits(v.x * scale);
    pk.y = f2bf_bits(v.y * scale);
    pk.z = f2bf_bits(v.z * scale);
    pk.w = f2bf_bits(v.w * scale);
    reinterpret_cast<ushort4*>(out)[i] = pk;
  }
}

// ---------------- fused 256x128 GEMM core: C_z = A * W_z^T for z in [0,NZ)
// (unchanged from R4/R5 -- verbatim last-green text)
template <int NZ>
__device__ __forceinline__ void gemm_fused_core(const bf16* __restrict__ A,
                                                const bf16* __restrict__ w0,
                                                const bf16* __restrict__ w1,
                                                const bf16* __restrict__ w2,
                                                int bx, int by,
                                                f32x4 (&acc)[NZ][4][4]) {
  __shared__ __align__(16) bf16 L[3][8192 + NZ * 4096];
  const int t = threadIdx.x;
  const int lane = t & 63;
  const int l15 = lane & 15;
  const int quad = (lane >> 4) & 3;
  const int wave = t >> 6;
  const int wm = (wave >> 1) * 64;  // 4 M-groups of 64 rows
  const int wn = (wave & 1) * 64;   // 2 N-groups of 64 cols
  const int K = 1024;

  const f32x4 zero = {0.f, 0.f, 0.f, 0.f};
#pragma unroll
  for (int z = 0; z < NZ; ++z)
#pragma unroll
    for (int m = 0; m < 4; ++m)
#pragma unroll
      for (int n = 0; n < 4; ++n) acc[z][m][n] = zero;

  const int srow = t >> 2;
  const int schunk = ((t & 3) ^ ((t >> 3) & 3)) * 8;
  const bf16* ga0 = A + (size_t)(by * 256 + srow) * K + schunk;
  const bf16* ga1 = ga0 + (size_t)128 * K;
  const bf16* ws[3] = {w0, w1, w2};
  const bf16* gw[NZ];
#pragma unroll
  for (int z = 0; z < NZ; ++z)
    gw[z] = ws[z] + (size_t)(bx * 128 + srow) * K + schunk;

  const int fsw = (quad ^ ((l15 >> 1) & 3)) * 8;
  const int arow = (wm + l15) * 32 + fsw;  // + m*512
  const int brow = (wn + l15) * 32 + fsw;  // + 8192 + z*4096 + n*512

  auto stage = [&](int kt) {
    bf16* Ld = &L[kt % 3][0];
    async_copy16(ga0 + kt * 32, Ld + t * 8);
    async_copy16(ga1 + kt * 32, Ld + 4096 + t * 8);
#pragma unroll
    for (int z = 0; z < NZ; ++z)
      async_copy16(gw[z] + kt * 32, Ld + 8192 + z * 4096 + t * 8);
  };

  stage(0);
  stage(1);
  if constexpr (NZ == 3)
    asm volatile("s_waitcnt vmcnt(5)" ::: "memory");
  else
    asm volatile("s_waitcnt vmcnt(3)" ::: "memory");
  __builtin_amdgcn_s_barrier();

  for (int T = 0; T < 32; ++T) {
    const bf16* Lb = &L[T % 3][0];
    short8 af[4];
#pragma unroll
    for (int m = 0; m < 4; ++m)
      af[m] = *reinterpret_cast<const short8*>(Lb + arow + m * 512);
    if (T <= 29) {
      stage(T + 2);
      if constexpr (NZ == 3)
        asm volatile("s_waitcnt vmcnt(5)" ::: "memory");
      else
        asm volatile("s_waitcnt vmcnt(3)" ::: "memory");
    } else {
      asm volatile("s_waitcnt vmcnt(0)" ::: "memory");
    }
    __builtin_amdgcn_s_barrier();
    asm volatile("s_waitcnt lgkmcnt(0)" ::: "memory");
    __builtin_amdgcn_sched_barrier(0);
    __builtin_amdgcn_s_setprio(1);
#pragma unroll
    for (int z = 0; z < NZ; ++z) {
      short8 bfr[4];
#pragma unroll
      for (int n = 0; n < 4; ++n)
        bfr[n] = *reinterpret_cast<const short8*>(Lb + 8192 + z * 4096 + brow + n * 512);
#pragma unroll
      for (int m = 0; m < 4; ++m)
#pragma unroll
        for (int n = 0; n < 4; ++n) acc[z][m][n] = MFMA_BF16(af[m], bfr[n], acc[z][m][n]);
    }
    __builtin_amdgcn_s_setprio(0);
    __builtin_amdgcn_sched_barrier(0);
    __builtin_amdgcn_s_barrier();
  }
}

// block id -> (bx, by): XCD x owns by in [4x,4x+4) x all 8 bx (L2 reuse).
__device__ __forceinline__ void xcd_map(int i, int& bx, int& by) {
  bx = (i >> 3) & 7;
  by = (i & 7) * 4 + (i >> 6);
}

// fused q/k/v projection: grid 256 blocks x 512 threads. z==2 (V) writes
// TRANSPOSED into vt[(b*1024 + col)*2048 + tau(t)].
__global__ __launch_bounds__(512, 2) void gemm_qkv(const bf16* __restrict__ x,
                                                   const bf16* __restrict__ wq,
                                                   const bf16* __restrict__ wk,
                                                   const bf16* __restrict__ wv,
                                                   bf16* __restrict__ q, bf16* __restrict__ k,
                                                   bf16* __restrict__ vt) {
  int bx, by;
  xcd_map(blockIdx.x, bx, by);
  f32x4 acc[3][4][4];
  gemm_fused_core<3>(x, wq, wk, wv, bx, by, acc);
  const int t = threadIdx.x, lane = t & 63, l15 = lane & 15, quad = (lane >> 4) & 3,
            wave = t >> 6;
  const int wm = (wave >> 1) * 64, wn = (wave & 1) * 64;
  const int rb = by * 256 + wm + quad * 4;
  const int cbb = bx * 128 + wn + l15;
#pragma unroll
  for (int z = 0; z < 2; ++z) {
    bf16* C = z ? k : q;
#pragma unroll
    for (int m = 0; m < 4; ++m)
#pragma unroll
      for (int n = 0; n < 4; ++n)
#pragma unroll
        for (int r = 0; r < 4; ++r)
          C[(size_t)(rb + m * 16 + r) * 1024 + cbb + n * 16] = __float2bfloat16(acc[z][m][n][r]);
  }
#pragma unroll
  for (int m = 0; m < 4; ++m)
#pragma unroll
    for (int n = 0; n < 4; ++n) {
      const int tg = rb + m * 16;
      const int col = cbb + n * 16;
      const int b = tg >> 11, tl = tg & 2047;
      const int tls = (tl & ~12) | ((tl & 4) << 1) | ((tl & 8) >> 1);  // tau
      ushort4 pk;
      pk.x = f2bf_bits(acc[2][m][n][0]);
      pk.y = f2bf_bits(acc[2][m][n][1]);
      pk.z = f2bf_bits(acc[2][m][n][2]);
      pk.w = f2bf_bits(acc[2][m][n][3]);
      *reinterpret_cast<ushort4*>(&vt[((size_t)(b * 1024 + col)) * 2048 + tls]) = pk;
    }
}

// output projection: same core at NZ=1, grid 256 blocks, fp32 out
__global__ __launch_bounds__(512, 2) void gemm_proj(const bf16* __restrict__ y,
                                                    const bf16* __restrict__ wp,
                                                    float* __restrict__ outp) {
  int bx, by;
  xcd_map(blockIdx.x, bx, by);
  f32x4 acc[1][4][4];
  gemm_fused_core<1>(y, wp, wp, wp, bx, by, acc);
  const int t = threadIdx.x, lane = t & 63, l15 = lane & 15, quad = (lane >> 4) & 3,
            wave = t >> 6;
  const int wm = (wave >> 1) * 64, wn = (wave & 1) * 64;
  const int rb = by * 256 + wm + quad * 4;
  const int cbb = bx * 128 + wn + l15;
#pragma unroll
  for (int m = 0; m < 4; ++m)
#pragma unroll
    for (int n = 0; n < 4; ++n)
#pragma unroll
      for (int r = 0; r < 4; ++r)
        outp[(size_t)(rb + m * 16 + r) * 1024 + cbb + n * 16] = acc[0][m][n][r];
}

// ----------------------------------------------------------- flash attention
// VERBATIM the R5 kernel (last green: 85.6us, 0 bank conflicts). KVBLK=64,
// grid (64 bh, 16 p), block p handles q-tiles p and 31-p, double-buffered
// K/V tiles, G4 3-bit XOR swizzle, swapped QK^T, cvt_pk + permlane32_swap
// P-redistribution (pi/tau key order), fixed-max softmax.
__global__ __launch_bounds__(256, 3) void attn(const bf16* __restrict__ qb,
                                               const bf16* __restrict__ kb,
                                               const bf16* __restrict__ vt,
                                               bf16* __restrict__ yb) {
  __shared__ __align__(16) bf16 Ks[2][4096];
  __shared__ __align__(16) bf16 Vs[2][4096];
  const int tid = threadIdx.x;
  const int lane = tid & 63, l15 = lane & 15, quad = lane >> 4, wave = tid >> 6;
  const int p = blockIdx.y;
  const int bh = blockIdx.x;
  const int b = bh >> 4, h = bh & 15;
  const size_t rowbase = (size_t)b * 2048;
  const int cb = h * 64;

  const int tlo = p, thi = 31 - p;
  const int gq0[2] = {tlo * 64 + wave * 16, thi * 64 + wave * 16};

  short8 aq[2][2];
#pragma unroll
  for (int g = 0; g < 2; ++g) {
    const bf16* qp = qb + (rowbase + gq0[g] + l15) * 1024 + cb + quad * 8;
    aq[g][0] = *reinterpret_cast<const short8*>(qp);
    aq[g][1] = *reinterpret_cast<const short8*>(qp + 32);
  }

  short8 ones;
#pragma unroll
  for (int i = 0; i < 8; ++i) ones[i] = (short)0x3F80;  // bf16 1.0

  f32x4 o[2][4], l4[2];
  const f32x4 zero = {0.f, 0.f, 0.f, 0.f};
#pragma unroll
  for (int g = 0; g < 2; ++g) {
#pragma unroll
    for (int dt = 0; dt < 4; ++dt) o[g][dt] = zero;
    l4[g] = zero;
  }

  // staging: thread tid owns LDS slots (row = i*32 + tid>>3, chunk = tid&7);
  // fetches global chunk (tid&7) ^ ((tid>>3)&7)  (f(row) = row&7).
  const int srow = tid >> 3;              // 0..31
  const int sc = (tid & 7) ^ (srow & 7);  // swizzled source chunk
  const bf16* kg = kb + (rowbase + srow) * 1024 + cb + sc * 8;
  const bf16* vg = vt + ((size_t)bh * 64 + srow) * 2048 + sc * 8;
  const int fx = l15 & 7;  // fragment-read XOR: row&7 = l15&7 for all frags

  const int nkt = thi + 1;
  // prologue: stage tile 0 (K rows 0-31, 32-63; V d-rows 0-31, 32-63)
  async_copy16(kg, &Ks[0][tid * 8]);
  async_copy16(kg + 32 * 1024, &Ks[0][2048 + tid * 8]);
  async_copy16(vg, &Vs[0][tid * 8]);
  async_copy16(vg + (size_t)32 * 2048, &Vs[0][2048 + tid * 8]);

  for (int kt = 0; kt < nkt; ++kt) {
    const int buf = kt & 1;
    __syncthreads();  // tile kt resident; prior reads of buf^1 done
    if (kt + 1 < nkt) {
      const bf16* kgn = kg + (size_t)(kt + 1) * 64 * 1024;
      const bf16* vgn = vg + (kt + 1) * 64;
      async_copy16(kgn, &Ks[buf ^ 1][tid * 8]);
      async_copy16(kgn + 32 * 1024, &Ks[buf ^ 1][2048 + tid * 8]);
      async_copy16(vgn, &Vs[buf ^ 1][tid * 8]);
      async_copy16(vgn + (size_t)32 * 2048, &Vs[buf ^ 1][2048 + tid * 8]);
    }
    const int k0g = kt * 64;

    // K fragments, shared by both q-groups: row = j*16+l15 (key), 8 d per reg
    short8 bk[4][2];
#pragma unroll
    for (int j = 0; j < 4; ++j)
#pragma unroll
      for (int ks = 0; ks < 2; ++ks)
        bk[j][ks] = *reinterpret_cast<const short8*>(
            &Ks[buf][(j * 16 + l15) * 64 + (((ks * 4 + quad) ^ fx)) * 8]);

#pragma unroll
    for (int g = 0; g < 2; ++g) {
      if (k0g > gq0[g] + 15) continue;
      // swapped QK^T: st[j] = K*Q^T (S^T). col = q = l15, row = k.
      f32x4 st[4];
#pragma unroll
      for (int j = 0; j < 4; ++j) {
        st[j] = MFMA_BF16(bk[j][0], aq[g][0], zero);
        st[j] = MFMA_BF16(bk[j][1], aq[g][1], st[j]);
      }
      const int rem = gq0[g] + 15 - k0g;  // >=0 when active (wave-uniform)
      const bool need_mask = (k0g + 63 > gq0[g]);
      unsigned w[4][2] = {{0u, 0u}, {0u, 0u}, {0u, 0u}, {0u, 0u}};
#pragma unroll
      for (int j = 0; j < 4; ++j) {
        if (j * 16 <= rem) {  // wave-uniform: skip fully-masked j-blocks
          float pw[4];
#pragma unroll
          for (int r = 0; r < 4; ++r) {
            float val = st[j][r];  // pre-scaled (folded into Wq)
            if (need_mask && (k0g + j * 16 + quad * 4 + r) > (gq0[g] + l15))
              val = -INFINITY;
            pw[r] = __builtin_amdgcn_exp2f(val);
          }
          w[j][0] = cvt_pk_bf16(pw[0], pw[1]);
          w[j][1] = cvt_pk_bf16(pw[2], pw[3]);
        }
      }
      // per 32-key half: permlane32_swap pair (2h, 2h+1) -> B-fragment bp;
      // slot k = half*32 + pi(quad*8+e), matching vt's tau order.
#pragma unroll
      for (int half = 0; half < 2; ++half) {
        uint2v s0 =
            __builtin_amdgcn_permlane32_swap(w[2 * half][0], w[2 * half + 1][0], false, false);
        uint2v s1 =
            __builtin_amdgcn_permlane32_swap(w[2 * half][1], w[2 * half + 1][1], false, false);
        uint4v u;
        u[0] = s0[0];
        u[1] = s1[0];
        u[2] = s0[1];
        u[3] = s1[1];
        const short8 bp = __builtin_bit_cast(short8, u);
#pragma unroll
        for (int dt = 0; dt < 4; ++dt) {
          const short8 av = *reinterpret_cast<const short8*>(
              &Vs[buf][(dt * 16 + l15) * 64 + (((half * 4 + quad) ^ fx)) * 8]);
          o[g][dt] = MFMA_BF16(av, bp, o[g][dt]);
        }
        l4[g] = MFMA_BF16(ones, bp, l4[g]);  // row sums of P (pi-invariant)
      }
    }
  }

  // epilogue: lane holds q = gq0[g]+l15, d = dt*16 + quad*4 + r (r contiguous)
#pragma unroll
  for (int g = 0; g < 2; ++g) {
    const float invl = 1.f / l4[g][0];
    bf16* yp = yb + (rowbase + gq0[g] + l15) * 1024 + cb + quad * 4;
#pragma unroll
    for (int dt = 0; dt < 4; ++dt) {
      ushort4 pk;
      pk.x = f2bf_bits(o[g][dt][0] * invl);
      pk.y = f2bf_bits(o[g][dt][1] * invl);
      pk.z = f2bf_bits(o[g][dt][2] * invl);
      pk.w = f2bf_bits(o[g][dt][3] * invl);
      *reinterpret_cast<ushort4*>(&yp[dt * 16]) = pk;
    }
  }
}

// ---------------------------------------------------------------------- launch
extern "C" void kernel_launch(void* const* d_in, const int* in_sizes, int n_in,
                              void* d_out, int out_size, void* d_ws, size_t ws_size,
                              hipStream_t stream) {
  const float* x = (const float*)d_in[0];
  const float* Wq = (const float*)d_in[1];
  const float* Wk = (const float*)d_in[2];
  const float* Wv = (const float*)d_in[3];
  const float* Wp = (const float*)d_in[4];
  float* out = (float*)d_out;

  const size_t MB = 1024 * 1024;
  char* ws = (char*)d_ws;
  bf16* xb = (bf16*)(ws);             // 16 MB; reused as yb after QKV
  bf16* qb = (bf16*)(ws + 16 * MB);   // 16 MB
  bf16* kb = (bf16*)(ws + 32 * MB);   // 16 MB
  bf16* vtb = (bf16*)(ws + 48 * MB);  // 16 MB, V transposed [bh][d][tau(t)]
  bf16* wqb = (bf16*)(ws + 64 * MB);  // 2 MB each
  bf16* wkb = (bf16*)(ws + 66 * MB);
  bf16* wvb = (bf16*)(ws + 68 * MB);
  bf16* wpb = (bf16*)(ws + 70 * MB);
  bf16* yb = xb;

  cvt_all<<<6144, 256, 0, stream>>>(x, Wq, Wk, Wv, Wp, xb, wqb, wkb, wvb, wpb);
  gemm_qkv<<<256, 512, 0, stream>>>(xb, wqb, wkb, wvb, qb, kb, vtb);
  attn<<<dim3(64, 16), 256, 0, stream>>>(qb, kb, vtb, yb);
  gemm_proj<<<256, 512, 0, stream>>>(yb, wpb, out);
}

// Round 9
// 232.740 us; speedup vs baseline: 1.2879x; 1.0389x over previous
//
#include <hip/hip_runtime.h>
#include <hip/hip_bf16.h>
#include <math.h>

typedef __hip_bfloat16 bf16;
typedef __attribute__((ext_vector_type(8))) short short8;
typedef __attribute__((ext_vector_type(4))) float f32x4;
typedef __attribute__((ext_vector_type(2))) unsigned uint2v;
typedef __attribute__((ext_vector_type(4))) unsigned uint4v;

#define MFMA_BF16(a, b, c) __builtin_amdgcn_mfma_f32_16x16x32_bf16((a), (b), (c), 0, 0, 0)

// async global->LDS, 16B per lane (m97 pattern). LDS dest must be base + lane*16.
__device__ __forceinline__ void async_copy16(const bf16* g, bf16* l) {
  __builtin_amdgcn_global_load_lds(
      (const __attribute__((address_space(1))) void*)g,
      (__attribute__((address_space(3))) void*)l,
      16, 0, 0);
}

__device__ __forceinline__ unsigned short f2bf_bits(float f) {
  bf16 h = __float2bfloat16(f);
  return *reinterpret_cast<unsigned short*>(&h);
}

// pack 2 f32 -> 2 bf16 in one u32 (lo = first arg). No builtin on gfx950 (m240).
__device__ __forceinline__ unsigned cvt_pk_bf16(float lo, float hi) {
  unsigned r;
  asm("v_cvt_pk_bf16_f32 %0, %1, %2" : "=v"(r) : "v"(lo), "v"(hi));
  return r;
}

// ------------------------------------------- all fp32 -> bf16 in one launch
// 2 float4 per thread (6144 blocks). Regions (in float4 units of 512/blk):
// [0,4096): x ; [4096,4608): Wq (pre-scaled 0.125*log2e) ; [4608,5120): Wk ;
// [5120,5632): Wv ; [5632,6144): Wp.
__global__ __launch_bounds__(256) void cvt_all(const float* __restrict__ x,
                                               const float* __restrict__ wq,
                                               const float* __restrict__ wk,
                                               const float* __restrict__ wv,
                                               const float* __restrict__ wp,
                                               bf16* __restrict__ xb, bf16* __restrict__ wqb,
                                               bf16* __restrict__ wkb, bf16* __restrict__ wvb,
                                               bf16* __restrict__ wpb) {
  const int bid = blockIdx.x;
  const float* in;
  bf16* out;
  int off;
  float scale = 1.0f;
  if (bid < 4096) {
    in = x; out = xb; off = bid;
  } else if (bid < 4608) {
    in = wq; out = wqb; off = bid - 4096;
    scale = 0.180336880111112f;  // 0.125 * log2(e) folded into Wq
  } else if (bid < 5120) {
    in = wk; out = wkb; off = bid - 4608;
  } else if (bid < 5632) {
    in = wv; out = wvb; off = bid - 5120;
  } else {
    in = wp; out = wpb; off = bid - 5632;
  }
  const int base = off * 512 + threadIdx.x * 2;
#pragma unroll
  for (int u = 0; u < 2; ++u) {
    const int i = base + u;
    float4 v = reinterpret_cast<const float4*>(in)[i];
    ushort4 pk;
    pk.x = f2bf_bits(v.x * scale);
    pk.y = f2bf_bits(v.y * scale);
    pk.z = f2bf_bits(v.z * scale);
    pk.w = f2bf_bits(v.w * scale);
    reinterpret_cast<ushort4*>(out)[i] = pk;
  }
}

// ---------------- fused 256x128 GEMM core: C_z = A * W_z^T for z in [0,NZ)
// (unchanged -- verbatim last-green text)
template <int NZ>
__device__ __forceinline__ void gemm_fused_core(const bf16* __restrict__ A,
                                                const bf16* __restrict__ w0,
                                                const bf16* __restrict__ w1,
                                                const bf16* __restrict__ w2,
                                                int bx, int by,
                                                f32x4 (&acc)[NZ][4][4]) {
  __shared__ __align__(16) bf16 L[3][8192 + NZ * 4096];
  const int t = threadIdx.x;
  const int lane = t & 63;
  const int l15 = lane & 15;
  const int quad = (lane >> 4) & 3;
  const int wave = t >> 6;
  const int wm = (wave >> 1) * 64;  // 4 M-groups of 64 rows
  const int wn = (wave & 1) * 64;   // 2 N-groups of 64 cols
  const int K = 1024;

  const f32x4 zero = {0.f, 0.f, 0.f, 0.f};
#pragma unroll
  for (int z = 0; z < NZ; ++z)
#pragma unroll
    for (int m = 0; m < 4; ++m)
#pragma unroll
      for (int n = 0; n < 4; ++n) acc[z][m][n] = zero;

  const int srow = t >> 2;
  const int schunk = ((t & 3) ^ ((t >> 3) & 3)) * 8;
  const bf16* ga0 = A + (size_t)(by * 256 + srow) * K + schunk;
  const bf16* ga1 = ga0 + (size_t)128 * K;
  const bf16* ws[3] = {w0, w1, w2};
  const bf16* gw[NZ];
#pragma unroll
  for (int z = 0; z < NZ; ++z)
    gw[z] = ws[z] + (size_t)(bx * 128 + srow) * K + schunk;

  const int fsw = (quad ^ ((l15 >> 1) & 3)) * 8;
  const int arow = (wm + l15) * 32 + fsw;  // + m*512
  const int brow = (wn + l15) * 32 + fsw;  // + 8192 + z*4096 + n*512

  auto stage = [&](int kt) {
    bf16* Ld = &L[kt % 3][0];
    async_copy16(ga0 + kt * 32, Ld + t * 8);
    async_copy16(ga1 + kt * 32, Ld + 4096 + t * 8);
#pragma unroll
    for (int z = 0; z < NZ; ++z)
      async_copy16(gw[z] + kt * 32, Ld + 8192 + z * 4096 + t * 8);
  };

  stage(0);
  stage(1);
  if constexpr (NZ == 3)
    asm volatile("s_waitcnt vmcnt(5)" ::: "memory");
  else
    asm volatile("s_waitcnt vmcnt(3)" ::: "memory");
  __builtin_amdgcn_s_barrier();

  for (int T = 0; T < 32; ++T) {
    const bf16* Lb = &L[T % 3][0];
    short8 af[4];
#pragma unroll
    for (int m = 0; m < 4; ++m)
      af[m] = *reinterpret_cast<const short8*>(Lb + arow + m * 512);
    if (T <= 29) {
      stage(T + 2);
      if constexpr (NZ == 3)
        asm volatile("s_waitcnt vmcnt(5)" ::: "memory");
      else
        asm volatile("s_waitcnt vmcnt(3)" ::: "memory");
    } else {
      asm volatile("s_waitcnt vmcnt(0)" ::: "memory");
    }
    __builtin_amdgcn_s_barrier();
    asm volatile("s_waitcnt lgkmcnt(0)" ::: "memory");
    __builtin_amdgcn_sched_barrier(0);
    __builtin_amdgcn_s_setprio(1);
#pragma unroll
    for (int z = 0; z < NZ; ++z) {
      short8 bfr[4];
#pragma unroll
      for (int n = 0; n < 4; ++n)
        bfr[n] = *reinterpret_cast<const short8*>(Lb + 8192 + z * 4096 + brow + n * 512);
#pragma unroll
      for (int m = 0; m < 4; ++m)
#pragma unroll
        for (int n = 0; n < 4; ++n) acc[z][m][n] = MFMA_BF16(af[m], bfr[n], acc[z][m][n]);
    }
    __builtin_amdgcn_s_setprio(0);
    __builtin_amdgcn_sched_barrier(0);
    __builtin_amdgcn_s_barrier();
  }
}

// block id -> (bx, by): XCD x owns by in [4x,4x+4) x all 8 bx (L2 reuse).
__device__ __forceinline__ void xcd_map(int i, int& bx, int& by) {
  bx = (i >> 3) & 7;
  by = (i & 7) * 4 + (i >> 6);
}

// fused q/k/v projection: grid 256 blocks x 512 threads. z==2 (V) writes
// TRANSPOSED into vt[(b*1024 + col)*2048 + tau(t)].
__global__ __launch_bounds__(512, 2) void gemm_qkv(const bf16* __restrict__ x,
                                                   const bf16* __restrict__ wq,
                                                   const bf16* __restrict__ wk,
                                                   const bf16* __restrict__ wv,
                                                   bf16* __restrict__ q, bf16* __restrict__ k,
                                                   bf16* __restrict__ vt) {
  int bx, by;
  xcd_map(blockIdx.x, bx, by);
  f32x4 acc[3][4][4];
  gemm_fused_core<3>(x, wq, wk, wv, bx, by, acc);
  const int t = threadIdx.x, lane = t & 63, l15 = lane & 15, quad = (lane >> 4) & 3,
            wave = t >> 6;
  const int wm = (wave >> 1) * 64, wn = (wave & 1) * 64;
  const int rb = by * 256 + wm + quad * 4;
  const int cbb = bx * 128 + wn + l15;
#pragma unroll
  for (int z = 0; z < 2; ++z) {
    bf16* C = z ? k : q;
#pragma unroll
    for (int m = 0; m < 4; ++m)
#pragma unroll
      for (int n = 0; n < 4; ++n)
#pragma unroll
        for (int r = 0; r < 4; ++r)
          C[(size_t)(rb + m * 16 + r) * 1024 + cbb + n * 16] = __float2bfloat16(acc[z][m][n][r]);
  }
#pragma unroll
  for (int m = 0; m < 4; ++m)
#pragma unroll
    for (int n = 0; n < 4; ++n) {
      const int tg = rb + m * 16;
      const int col = cbb + n * 16;
      const int b = tg >> 11, tl = tg & 2047;
      const int tls = (tl & ~12) | ((tl & 4) << 1) | ((tl & 8) >> 1);  // tau
      ushort4 pk;
      pk.x = f2bf_bits(acc[2][m][n][0]);
      pk.y = f2bf_bits(acc[2][m][n][1]);
      pk.z = f2bf_bits(acc[2][m][n][2]);
      pk.w = f2bf_bits(acc[2][m][n][3]);
      *reinterpret_cast<ushort4*>(&vt[((size_t)(b * 1024 + col)) * 2048 + tls]) = pk;
    }
}

// output projection: same core at NZ=1, grid 256 blocks, fp32 out
__global__ __launch_bounds__(512, 2) void gemm_proj(const bf16* __restrict__ y,
                                                    const bf16* __restrict__ wp,
                                                    float* __restrict__ outp) {
  int bx, by;
  xcd_map(blockIdx.x, bx, by);
  f32x4 acc[1][4][4];
  gemm_fused_core<1>(y, wp, wp, wp, bx, by, acc);
  const int t = threadIdx.x, lane = t & 63, l15 = lane & 15, quad = (lane >> 4) & 3,
            wave = t >> 6;
  const int wm = (wave >> 1) * 64, wn = (wave & 1) * 64;
  const int rb = by * 256 + wm + quad * 4;
  const int cbb = bx * 128 + wn + l15;
#pragma unroll
  for (int m = 0; m < 4; ++m)
#pragma unroll
    for (int n = 0; n < 4; ++n)
#pragma unroll
      for (int r = 0; r < 4; ++r)
        outp[(size_t)(rb + m * 16 + r) * 1024 + cbb + n * 16] = acc[0][m][n][r];
}

// ----------------------------------------------------------- flash attention
// v9: 8-wave paired blocks. Grid stays (64 bh, 16 p) and the p/(31-p) pairing
// (equal-length blocks) is preserved -- the ONLY change vs the green R5/R8
// kernel is that the two q-groups now live on different WAVES of a 512-thread
// block (waves 0-3: tlo, waves 4-7: thi) instead of both on each wave:
//  * per-wave body = R5's per-g body with g fixed (guard k0g <= gq0+15 now
//    wraps compute instead of `continue`; wave-uniform as before).
//  * staging: 512 threads -> ONE async_copy16 per K/V buffer per thread
//    (srow = tid>>3 covers all 64 rows; same f(row)=row&7 swizzle; final LDS
//    layout byte-identical to R5's two-copy scheme).
//  * K/V tiles now shared by 8 waves; DMA per wave halves.
//  * occupancy: 1024 blocks x 8 waves; ~3 blocks/CU resident (~24 waves/CU)
//    vs R5's 16 -> 1.5x TLP for the latency-bound chain.
__global__ __launch_bounds__(512, 2) void attn(const bf16* __restrict__ qb,
                                               const bf16* __restrict__ kb,
                                               const bf16* __restrict__ vt,
                                               bf16* __restrict__ yb) {
  __shared__ __align__(16) bf16 Ks[2][4096];
  __shared__ __align__(16) bf16 Vs[2][4096];
  const int tid = threadIdx.x;
  const int lane = tid & 63, l15 = lane & 15, quad = (lane >> 4) & 3, wave = tid >> 6;
  const int p = blockIdx.y;
  const int bh = blockIdx.x;
  const int b = bh >> 4, h = bh & 15;
  const size_t rowbase = (size_t)b * 2048;
  const int cb = h * 64;

  const int tlo = p, thi = 31 - p;
  const int g = wave >> 2;   // 0: tlo tile, 1: thi tile
  const int w4 = wave & 3;   // 16-row slice within the tile
  const int qt = g ? thi : tlo;
  const int gq0 = qt * 64 + w4 * 16;

  short8 aq[2];
  {
    const bf16* qp = qb + (rowbase + gq0 + l15) * 1024 + cb + quad * 8;
    aq[0] = *reinterpret_cast<const short8*>(qp);
    aq[1] = *reinterpret_cast<const short8*>(qp + 32);
  }

  short8 ones;
#pragma unroll
  for (int i = 0; i < 8; ++i) ones[i] = (short)0x3F80;  // bf16 1.0

  f32x4 o[4], l4;
  const f32x4 zero = {0.f, 0.f, 0.f, 0.f};
#pragma unroll
  for (int dt = 0; dt < 4; ++dt) o[dt] = zero;
  l4 = zero;

  // staging: thread tid owns LDS slot (row = tid>>3 in [0,64), chunk = tid&7);
  // fetches global chunk (tid&7) ^ (row&7)  (f(row) = row&7, as R5).
  const int srow = tid >> 3;              // 0..63
  const int sc = (tid & 7) ^ (srow & 7);  // swizzled source chunk
  const bf16* kg = kb + (rowbase + srow) * 1024 + cb + sc * 8;
  const bf16* vg = vt + ((size_t)bh * 64 + srow) * 2048 + sc * 8;
  const int fx = l15 & 7;  // fragment-read XOR: row&7 = l15&7 for all frags

  const int nkt = thi + 1;
  // prologue: stage tile 0 (K keys 0-63; V d-rows 0-63)
  async_copy16(kg, &Ks[0][tid * 8]);
  async_copy16(vg, &Vs[0][tid * 8]);

  for (int kt = 0; kt < nkt; ++kt) {
    const int buf = kt & 1;
    __syncthreads();  // tile kt resident; prior reads of buf^1 done
    if (kt + 1 < nkt) {
      async_copy16(kg + (size_t)(kt + 1) * 64 * 1024, &Ks[buf ^ 1][tid * 8]);
      async_copy16(vg + (kt + 1) * 64, &Vs[buf ^ 1][tid * 8]);
    }
    const int k0g = kt * 64;

    if (k0g <= gq0 + 15) {  // wave-uniform activity guard (== R5's per-g guard)
      // K fragments: row = j*16+l15 (key), 8 d per reg
      short8 bk[4][2];
#pragma unroll
      for (int j = 0; j < 4; ++j)
#pragma unroll
        for (int ks = 0; ks < 2; ++ks)
          bk[j][ks] = *reinterpret_cast<const short8*>(
              &Ks[buf][(j * 16 + l15) * 64 + (((ks * 4 + quad) ^ fx)) * 8]);

      // swapped QK^T: st[j] = K*Q^T (S^T). col = q = l15, row = k.
      f32x4 st[4];
#pragma unroll
      for (int j = 0; j < 4; ++j) {
        st[j] = MFMA_BF16(bk[j][0], aq[0], zero);
        st[j] = MFMA_BF16(bk[j][1], aq[1], st[j]);
      }
      const int rem = gq0 + 15 - k0g;  // >= 0 when active (wave-uniform)
      const bool need_mask = (k0g + 63 > gq0);
      unsigned w[4][2] = {{0u, 0u}, {0u, 0u}, {0u, 0u}, {0u, 0u}};
#pragma unroll
      for (int j = 0; j < 4; ++j) {
        if (j * 16 <= rem) {  // wave-uniform: skip fully-masked j-blocks
          float pw[4];
#pragma unroll
          for (int r = 0; r < 4; ++r) {
            float val = st[j][r];  // pre-scaled (folded into Wq)
            if (need_mask && (k0g + j * 16 + quad * 4 + r) > (gq0 + l15))
              val = -INFINITY;
            pw[r] = __builtin_amdgcn_exp2f(val);
          }
          w[j][0] = cvt_pk_bf16(pw[0], pw[1]);
          w[j][1] = cvt_pk_bf16(pw[2], pw[3]);
        }
      }
      // per 32-key half: permlane32_swap pair (2h, 2h+1) -> B-fragment bp;
      // slot k = half*32 + pi(quad*8+e), matching vt's tau order.
#pragma unroll
      for (int half = 0; half < 2; ++half) {
        uint2v s0 =
            __builtin_amdgcn_permlane32_swap(w[2 * half][0], w[2 * half + 1][0], false, false);
        uint2v s1 =
            __builtin_amdgcn_permlane32_swap(w[2 * half][1], w[2 * half + 1][1], false, false);
        uint4v u;
        u[0] = s0[0];
        u[1] = s1[0];
        u[2] = s0[1];
        u[3] = s1[1];
        const short8 bp = __builtin_bit_cast(short8, u);
#pragma unroll
        for (int dt = 0; dt < 4; ++dt) {
          const short8 av = *reinterpret_cast<const short8*>(
              &Vs[buf][(dt * 16 + l15) * 64 + (((half * 4 + quad) ^ fx)) * 8]);
          o[dt] = MFMA_BF16(av, bp, o[dt]);
        }
        l4 = MFMA_BF16(ones, bp, l4);  // row sums of P (pi-invariant)
      }
    }
  }

  // epilogue: lane holds q = gq0+l15, d = dt*16 + quad*4 + r (r contiguous)
  {
    const float invl = 1.f / l4[0];
    bf16* yp = yb + (rowbase + gq0 + l15) * 1024 + cb + quad * 4;
#pragma unroll
    for (int dt = 0; dt < 4; ++dt) {
      ushort4 pk;
      pk.x = f2bf_bits(o[dt][0] * invl);
      pk.y = f2bf_bits(o[dt][1] * invl);
      pk.z = f2bf_bits(o[dt][2] * invl);
      pk.w = f2bf_bits(o[dt][3] * invl);
      *reinterpret_cast<ushort4*>(&yp[dt * 16]) = pk;
    }
  }
}

// ---------------------------------------------------------------------- launch
extern "C" void kernel_launch(void* const* d_in, const int* in_sizes, int n_in,
                              void* d_out, int out_size, void* d_ws, size_t ws_size,
                              hipStream_t stream) {
  const float* x = (const float*)d_in[0];
  const float* Wq = (const float*)d_in[1];
  const float* Wk = (const float*)d_in[2];
  const float* Wv = (const float*)d_in[3];
  const float* Wp = (const float*)d_in[4];
  float* out = (float*)d_out;

  const size_t MB = 1024 * 1024;
  char* ws = (char*)d_ws;
  bf16* xb = (bf16*)(ws);             // 16 MB; reused as yb after QKV
  bf16* qb = (bf16*)(ws + 16 * MB);   // 16 MB
  bf16* kb = (bf16*)(ws + 32 * MB);   // 16 MB
  bf16* vtb = (bf16*)(ws + 48 * MB);  // 16 MB, V transposed [bh][d][tau(t)]
  bf16* wqb = (bf16*)(ws + 64 * MB);  // 2 MB each
  bf16* wkb = (bf16*)(ws + 66 * MB);
  bf16* wvb = (bf16*)(ws + 68 * MB);
  bf16* wpb = (bf16*)(ws + 70 * MB);
  bf16* yb = xb;

  cvt_all<<<6144, 256, 0, stream>>>(x, Wq, Wk, Wv, Wp, xb, wqb, wkb, wvb, wpb);
  gemm_qkv<<<256, 512, 0, stream>>>(xb, wqb, wkb, wvb, qb, kb, vtb);
  attn<<<dim3(64, 16), 512, 0, stream>>>(qb, kb, vtb, yb);
  gemm_proj<<<256, 512, 0, stream>>>(yb, wpb, out);
}